// Round 6
// baseline (815.665 us; speedup 1.0000x reference)
//
#include <hip/hip_runtime.h>
#include <hip/hip_bf16.h>
#include <stdint.h>

// Shapes: B=32, L=256, D=1024, ALIGN=1024, FF=2048, NC=3
// Precision plan:
//  - F proj, E scores: bf16x3 split (~fp32) -- the softmax-sensitive path
//  - attn, betas/alphas, V=tanh(Cat@W_G): fp16 single (store rounding dominates)
//  - classifier: fp32 VALU skinny GEMMs (exact, M=32 is tiny)
// R6: split GEMM staging reverted to SYNC (VGPR roundtrip, padded LDS) --
// compiler software-pipelines next-iter global loads across the MFMA block;
// async global_load_lds regressed here (R5: +169 us) because the 48-MFMA/iter
// split kernel had nothing to hide the full HBM latency behind within a wave.

typedef __attribute__((ext_vector_type(8))) short    short8_t;   // 8 bf16
typedef __attribute__((ext_vector_type(4))) float    float4_t;
typedef __attribute__((ext_vector_type(8))) _Float16 half8_t;
typedef __attribute__((ext_vector_type(4))) _Float16 half4_t;

#define DEVI static __device__ __forceinline__

DEVI short f2bf(float f) {
  union { float f; unsigned u; } v; v.f = f;
  unsigned r = v.u + 0x7fffu + ((v.u >> 16) & 1u);   // RNE
  return (short)(r >> 16);
}
DEVI float bf2f(short s) {
  union { unsigned u; float f; } v;
  v.u = ((unsigned)(unsigned short)s) << 16;
  return v.f;
}
DEVI void split2(float x, short& hi, short& lo) {
  hi = f2bf(x);
  lo = f2bf(x - bf2f(hi));
}
DEVI float fast_tanh(float x) {
  float e = __expf(2.0f * x);
  return 1.0f - 2.0f / (e + 1.0f);
}
DEVI void gload16(const void* g, void* l) {
  // async global->LDS, 16B/lane; LDS dest = wave-uniform base + lane*16
  __builtin_amdgcn_global_load_lds(
      (const __attribute__((address_space(1))) void*)g,
      (__attribute__((address_space(3))) void*)l, 16, 0, 0);
}

// ---------------------------------------------------------------------------
// Split-bf16 NT GEMM (A=Ah+Al, B=Bh+Bl), 128x128 tile, BK=32, 4 waves,
// 3 MFMAs per product (hh,hl,lh). SYNC staging (VGPR roundtrip, [40] pad).
// blockIdx.z = batch*kslices + kslice.
// OUT_MODE: 0 = fp32 atomicAdd (split-K; C pre-zeroed), 1 = split bf16 store.
// ---------------------------------------------------------------------------
template <int DO_TANH, int OUT_MODE>
__global__ __launch_bounds__(256) void gemm_nt_split(
    const short* __restrict__ Ah, const short* __restrict__ Al, int lda, long sA,
    const short* __restrict__ Bh, const short* __restrict__ Bl, int ldb, long sB,
    void* __restrict__ Ch, void* __restrict__ Cl, int ldc, long sC,
    int M, int K, int kslices)
{
  __shared__ __align__(16) short Ash[128][40];
  __shared__ __align__(16) short Asl[128][40];
  __shared__ __align__(16) short Bsh[128][40];
  __shared__ __align__(16) short Bsl[128][40];

  const int z  = blockIdx.z;
  const int zb = z / kslices;
  const int zk = z - zb * kslices;
  const int Ksub = K / kslices;
  const int kbeg = zk * Ksub, kend = kbeg + Ksub;

  Ah += (size_t)zb * sA;  Al += (size_t)zb * sA;
  Bh += (size_t)zb * sB;  Bl += (size_t)zb * sB;

  const int row0 = blockIdx.x * 128;
  const int col0 = blockIdx.y * 128;

  const int t    = threadIdx.x;
  const int lane = t & 63;
  const int wave = t >> 6;
  const int wr = wave >> 1, wc = wave & 1;
  const int m15 = lane & 15, q = lane >> 4;

  float4_t acc[4][4];
#pragma unroll
  for (int i = 0; i < 4; ++i)
#pragma unroll
    for (int j = 0; j < 4; ++j) acc[i][j] = (float4_t)0.0f;

  for (int k0 = kbeg; k0 < kend; k0 += 32) {
#pragma unroll
    for (int i = 0; i < 2; ++i) {
      int c  = t + 256 * i;       // 0..511
      int r  = c >> 2;            // 0..127
      int kc = (c & 3) << 3;      // 0,8,16,24
      size_t ao = (size_t)(row0 + r) * lda + k0 + kc;
      size_t bo = (size_t)(col0 + r) * ldb + k0 + kc;
      *(int4*)(&Ash[r][kc]) = *(const int4*)(Ah + ao);
      *(int4*)(&Asl[r][kc]) = *(const int4*)(Al + ao);
      *(int4*)(&Bsh[r][kc]) = *(const int4*)(Bh + bo);
      *(int4*)(&Bsl[r][kc]) = *(const int4*)(Bl + bo);
    }
    __syncthreads();

    short8_t ah[4], al[4];
#pragma unroll
    for (int i = 0; i < 4; ++i) {
      ah[i] = *(const short8_t*)(&Ash[wr * 64 + i * 16 + m15][q * 8]);
      al[i] = *(const short8_t*)(&Asl[wr * 64 + i * 16 + m15][q * 8]);
    }
#pragma unroll
    for (int j = 0; j < 4; ++j) {
      short8_t bh = *(const short8_t*)(&Bsh[wc * 64 + j * 16 + m15][q * 8]);
      short8_t bl = *(const short8_t*)(&Bsl[wc * 64 + j * 16 + m15][q * 8]);
#pragma unroll
      for (int i = 0; i < 4; ++i) {
        acc[i][j] = __builtin_amdgcn_mfma_f32_16x16x32_bf16(ah[i], bh, acc[i][j], 0, 0, 0);
        acc[i][j] = __builtin_amdgcn_mfma_f32_16x16x32_bf16(ah[i], bl, acc[i][j], 0, 0, 0);
        acc[i][j] = __builtin_amdgcn_mfma_f32_16x16x32_bf16(al[i], bh, acc[i][j], 0, 0, 0);
      }
    }
    __syncthreads();
  }

  short* Chs = (short*)Ch + (size_t)zb * sC;
  short* Cls = (short*)Cl + (size_t)zb * sC;
  float* Cf  = (float*)Ch + (size_t)zb * sC;
#pragma unroll
  for (int i = 0; i < 4; ++i) {
#pragma unroll
    for (int r = 0; r < 4; ++r) {
      int gm = row0 + wr * 64 + i * 16 + q * 4 + r;
      if (gm < M) {
#pragma unroll
        for (int j = 0; j < 4; ++j) {
          int gn = col0 + wc * 64 + j * 16 + m15;
          float v = acc[i][j][r];
          if (DO_TANH) v = fast_tanh(v);
          if (OUT_MODE == 0) {
            atomicAdd(&Cf[(size_t)gm * ldc + gn], v);
          } else {
            short hi, lo; split2(v, hi, lo);
            Chs[(size_t)gm * ldc + gn] = hi;
            Cls[(size_t)gm * ldc + gn] = lo;
          }
        }
      }
    }
  }
}

// ---------------------------------------------------------------------------
// fp16 single-pass NT GEMM, BK=64, async staging, XOR-swizzled LDS.
// MODE 1: fp16 store (betas/alphas; batched via blockIdx.z)
// MODE 2: tanh + column-sum -> agg (V: 16384 rows = [Cat1;Cat2], agg[32][4096])
// ---------------------------------------------------------------------------
template <int MODE>
__global__ __launch_bounds__(256) void gemm_f16(
    const _Float16* __restrict__ A, int lda, long sA,
    const _Float16* __restrict__ B, int ldb, long sB,
    _Float16* __restrict__ C, int ldc, long sC,
    int K, float* __restrict__ agg)
{
  __shared__ __align__(16) _Float16 As[2 * 128 * 32];
  __shared__ __align__(16) _Float16 Bs[2 * 128 * 32];

  const int z = blockIdx.z;
  A += (size_t)z * sA;
  B += (size_t)z * sB;

  const int row0 = blockIdx.x * 128;
  const int col0 = blockIdx.y * 128;
  const int t = threadIdx.x, lane = t & 63, wave = t >> 6;
  const int wr = wave >> 1, wc = wave & 1;
  const int m15 = lane & 15, q = lane >> 4;

  const int srow = wave * 32 + (lane >> 2);
  const int cg   = ((lane & 3) ^ ((lane >> 3) & 3)) * 8;
  const _Float16* gA0 = A + (size_t)(row0 + srow) * lda + cg;
  const _Float16* gA1 = gA0 + (size_t)16 * lda;
  const _Float16* gB0 = B + (size_t)(col0 + srow) * ldb + cg;
  const _Float16* gB1 = gB0 + (size_t)16 * ldb;
  const _Float16* gA0b = gA0 + 32;
  const _Float16* gA1b = gA1 + 32;
  const _Float16* gB0b = gB0 + 32;
  const _Float16* gB1b = gB1 + 32;
  _Float16* lA0  = &As[(wave * 32) * 32];
  _Float16* lA1  = &As[(wave * 32 + 16) * 32];
  _Float16* lB0  = &Bs[(wave * 32) * 32];
  _Float16* lB1  = &Bs[(wave * 32 + 16) * 32];
  _Float16* lA0b = lA0 + 4096;
  _Float16* lA1b = lA1 + 4096;
  _Float16* lB0b = lB0 + 4096;
  _Float16* lB1b = lB1 + 4096;

  const int fs = (q ^ ((m15 >> 1) & 3)) * 8;
  int aoff[4], boff[4];
#pragma unroll
  for (int i = 0; i < 4; ++i) {
    aoff[i] = (wr * 64 + i * 16 + m15) * 32 + fs;
    boff[i] = (wc * 64 + i * 16 + m15) * 32 + fs;
  }

  float4_t acc[4][4];
#pragma unroll
  for (int i = 0; i < 4; ++i)
#pragma unroll
    for (int j = 0; j < 4; ++j) acc[i][j] = (float4_t)0.0f;

  for (int k0 = 0; k0 < K; k0 += 64) {
    gload16(gA0, lA0);  gload16(gA1, lA1);
    gload16(gB0, lB0);  gload16(gB1, lB1);
    gload16(gA0b, lA0b); gload16(gA1b, lA1b);
    gload16(gB0b, lB0b); gload16(gB1b, lB1b);
    gA0 += 64; gA1 += 64; gB0 += 64; gB1 += 64;
    gA0b += 64; gA1b += 64; gB0b += 64; gB1b += 64;
    __syncthreads();

#pragma unroll
    for (int h = 0; h < 2; ++h) {
      half8_t af[4], bfr[4];
#pragma unroll
      for (int i = 0; i < 4; ++i) af[i]  = *(const half8_t*)&As[h * 4096 + aoff[i]];
#pragma unroll
      for (int j = 0; j < 4; ++j) bfr[j] = *(const half8_t*)&Bs[h * 4096 + boff[j]];
#pragma unroll
      for (int i = 0; i < 4; ++i)
#pragma unroll
        for (int j = 0; j < 4; ++j)
          acc[i][j] = __builtin_amdgcn_mfma_f32_16x16x32_f16(af[i], bfr[j], acc[i][j], 0, 0, 0);
    }
    __syncthreads();
  }

  if (MODE == 2) {
    const int half_ = row0 >= 8192;
    const int b     = (row0 & 8191) >> 8;
#pragma unroll
    for (int j = 0; j < 4; ++j) {
      float s = 0.0f;
#pragma unroll
      for (int i = 0; i < 4; ++i)
#pragma unroll
        for (int r = 0; r < 4; ++r) s += fast_tanh(acc[i][j][r]);
      s += __shfl_xor(s, 16);
      s += __shfl_xor(s, 32);
      if (q == 0) {
        int col = col0 + wc * 64 + j * 16 + m15;
        atomicAdd(&agg[(size_t)b * 4096 + half_ * 2048 + col], s);
      }
    }
  } else {
    _Float16* Cp = C + (size_t)z * sC;
#pragma unroll
    for (int i = 0; i < 4; ++i)
#pragma unroll
      for (int r = 0; r < 4; ++r) {
        int gm = row0 + wr * 64 + i * 16 + q * 4 + r;
#pragma unroll
        for (int j = 0; j < 4; ++j) {
          int gn = col0 + wc * 64 + j * 16 + m15;
          Cp[(size_t)gm * ldc + gn] = (_Float16)acc[i][j][r];
        }
      }
  }
}

// --- fused input: P/H -> split bf16 planes + fp16 Cat left half + fp16 PH^T ---
// grid (32 c-tiles, 8 r-tiles, 64): z<32 = P batch z, z>=32 = H batch z-32
__global__ __launch_bounds__(256) void fused_in(
    const float* __restrict__ P, const float* __restrict__ Hh,
    short* __restrict__ oh, short* __restrict__ ol,
    _Float16* __restrict__ cat, _Float16* __restrict__ phT)
{
  __shared__ float tile[32][33];
  const int z = blockIdx.z;
  const float* in = (z < 32 ? P : Hh) + (size_t)(z & 31) * (256 * 1024);
  const int tx = threadIdx.x & 31, ty = threadIdx.x >> 5;
  const int c0 = blockIdx.x * 32, r0 = blockIdx.y * 32;
#pragma unroll
  for (int i = 0; i < 4; ++i) {
    int r = ty + i * 8;
    float v = in[(size_t)(r0 + r) * 1024 + c0 + tx];
    tile[r][tx] = v;
    size_t grow = (size_t)z * 256 + r0 + r;   // 0..16383 ([P;H] row)
    short hi, lo; split2(v, hi, lo);
    oh[grow * 1024 + c0 + tx] = hi;
    ol[grow * 1024 + c0 + tx] = lo;
    cat[grow * 2048 + c0 + tx] = (_Float16)v;
  }
  __syncthreads();
  _Float16* o = phT + (size_t)z * (1024 * 256);
#pragma unroll
  for (int i = 0; i < 4; ++i) {
    int cc = ty + i * 8;
    o[(size_t)(c0 + cc) * 256 + r0 + tx] = (_Float16)tile[tx][cc];
  }
}

// --- fp32 -> split bf16 transpose: out[c][r] ---
__global__ __launch_bounds__(256) void transpose_split(
    const float* __restrict__ in, short* __restrict__ oh, short* __restrict__ ol,
    int R, int C)
{
  __shared__ float tile[32][33];
  const int tx = threadIdx.x & 31, ty = threadIdx.x >> 5;
  const int c0 = blockIdx.x * 32, r0 = blockIdx.y * 32;
#pragma unroll
  for (int i = 0; i < 4; ++i) {
    int r = ty + i * 8;
    tile[r][tx] = in[(size_t)(r0 + r) * C + c0 + tx];
  }
  __syncthreads();
#pragma unroll
  for (int i = 0; i < 4; ++i) {
    int cc = ty + i * 8;
    float v = tile[tx][cc];
    short hi, lo; split2(v, hi, lo);
    size_t o = (size_t)(c0 + cc) * R + r0 + tx;
    oh[o] = hi;
    ol[o] = lo;
  }
}

// --- fp32 -> fp16 transpose: out[c][r] ---
__global__ __launch_bounds__(256) void transpose_f16(
    const float* __restrict__ in, _Float16* __restrict__ out, int R, int C)
{
  __shared__ float tile[32][33];
  const int tx = threadIdx.x & 31, ty = threadIdx.x >> 5;
  const int c0 = blockIdx.x * 32, r0 = blockIdx.y * 32;
#pragma unroll
  for (int i = 0; i < 4; ++i) {
    int r = ty + i * 8;
    tile[r][tx] = in[(size_t)(r0 + r) * C + c0 + tx];
  }
  __syncthreads();
#pragma unroll
  for (int i = 0; i < 4; ++i) {
    int cc = ty + i * 8;
    out[(size_t)(c0 + cc) * R + r0 + tx] = (_Float16)tile[tx][cc];
  }
}

// --- fp16 [256x256] batched transpose (attn -> attnT), bit-copy as short ---
__global__ __launch_bounds__(256) void transpose_b2b(
    const short* __restrict__ in, short* __restrict__ out,
    int R, int C, long sIn, long sOut)
{
  __shared__ short tile[32][33];
  in  += (size_t)blockIdx.z * sIn;
  out += (size_t)blockIdx.z * sOut;
  const int tx = threadIdx.x & 31, ty = threadIdx.x >> 5;
  const int c0 = blockIdx.x * 32, r0 = blockIdx.y * 32;
#pragma unroll
  for (int i = 0; i < 4; ++i) {
    int r = ty + i * 8;
    tile[r][tx] = in[(size_t)(r0 + r) * C + c0 + tx];
  }
  __syncthreads();
#pragma unroll
  for (int i = 0; i < 4; ++i) {
    int cc = ty + i * 8;
    out[(size_t)(c0 + cc) * R + r0 + tx] = tile[tx][cc];
  }
}

__global__ __launch_bounds__(256) void zero_f32(float* __restrict__ p, int n)
{
  int i = blockIdx.x * 256 + threadIdx.x;
  if (i < n) p[i] = 0.0f;
}

// --- softmax over rows of 256 (one wave per row), fp32 -> fp16 ---
__global__ __launch_bounds__(256) void softmax_rows(
    const float* __restrict__ e, _Float16* __restrict__ attn)
{
  const int row  = blockIdx.x * 4 + (threadIdx.x >> 6);
  const int lane = threadIdx.x & 63;
  const float4 v = *(const float4*)&e[(size_t)row * 256 + lane * 4];
  float m = fmaxf(fmaxf(v.x, v.y), fmaxf(v.z, v.w));
#pragma unroll
  for (int off = 32; off; off >>= 1) m = fmaxf(m, __shfl_xor(m, off));
  float e0 = __expf(v.x - m), e1 = __expf(v.y - m);
  float e2 = __expf(v.z - m), e3 = __expf(v.w - m);
  float s = e0 + e1 + e2 + e3;
#pragma unroll
  for (int off = 32; off; off >>= 1) s += __shfl_xor(s, off);
  float inv = 1.0f / s;
  half4_t o;
  o.x = (_Float16)(e0 * inv); o.y = (_Float16)(e1 * inv);
  o.z = (_Float16)(e2 * inv); o.w = (_Float16)(e3 * inv);
  *(half4_t*)&attn[(size_t)row * 256 + lane * 4] = o;
}

// --- fp32 skinny GEMM: part[ks][32][N] = A[32][KA] @ W[KA][N] (k-slice ks) ---
// A reads are wave-uniform -> scalar loads; W reads coalesced over n.
__global__ __launch_bounds__(256) void skinny_gemm(
    const float* __restrict__ A, int lda,
    const float* __restrict__ W, int N, int Kslice,
    float* __restrict__ part)
{
  const int n  = blockIdx.x * 256 + threadIdx.x;
  const int k0 = blockIdx.y * Kslice;
  float acc[32];
#pragma unroll
  for (int m = 0; m < 32; ++m) acc[m] = 0.0f;
  for (int k = k0; k < k0 + Kslice; ++k) {
    float w = W[(size_t)k * N + n];
#pragma unroll
    for (int m = 0; m < 32; ++m)
      acc[m] = fmaf(A[m * lda + k], w, acc[m]);
  }
  float* pp = part + (size_t)blockIdx.y * 32 * N;
#pragma unroll
  for (int m = 0; m < 32; ++m) pp[(size_t)m * N + n] = acc[m];
}

// --- out[i] = tanh(bias[i & 2047] + sum_s part[s*n + i]) ---
__global__ __launch_bounds__(256) void reduce_bias_tanh(
    const float* __restrict__ part, const float* __restrict__ bias,
    float* __restrict__ outp, int n, int slices)
{
  int i = blockIdx.x * 256 + threadIdx.x;
  if (i >= n) return;
  float s = bias[i & 2047];
  for (int sl = 0; sl < slices; ++sl) s += part[(size_t)sl * n + i];
  outp[i] = fast_tanh(s);
}

// --- logits: block b: out[b] = tanh(sum_s c2p[s][b] + b2) @ W3 + b3 ---
__global__ __launch_bounds__(256) void logits_red(
    const float* __restrict__ part, const float* __restrict__ b2,
    const float* __restrict__ W3, const float* __restrict__ b3,
    float* __restrict__ out, int slices)
{
  const int b = blockIdx.x, t = threadIdx.x;
  float p0 = 0.f, p1 = 0.f, p2 = 0.f;
  for (int k = t; k < 2048; k += 256) {
    float a = b2[k];
    for (int sl = 0; sl < slices; ++sl)
      a += part[((size_t)sl * 32 + b) * 2048 + k];
    a = fast_tanh(a);
    p0 += a * W3[k * 3 + 0];
    p1 += a * W3[k * 3 + 1];
    p2 += a * W3[k * 3 + 2];
  }
#pragma unroll
  for (int off = 32; off; off >>= 1) {
    p0 += __shfl_xor(p0, off);
    p1 += __shfl_xor(p1, off);
    p2 += __shfl_xor(p2, off);
  }
  __shared__ float red[4][3];
  if ((t & 63) == 0) {
    red[t >> 6][0] = p0; red[t >> 6][1] = p1; red[t >> 6][2] = p2;
  }
  __syncthreads();
  if (t < 3) out[b * 3 + t] = b3[t] + red[0][t] + red[1][t] + red[2][t] + red[3][t];
}

extern "C" void kernel_launch(void* const* d_in, const int* in_sizes, int n_in,
                              void* d_out, int out_size, void* d_ws, size_t ws_size,
                              hipStream_t stream) {
  (void)in_sizes; (void)n_in; (void)out_size; (void)ws_size;
  const float* P   = (const float*)d_in[0];
  const float* H   = (const float*)d_in[1];
  const float* W_F = (const float*)d_in[2];
  const float* W_G = (const float*)d_in[3];
  const float* W1  = (const float*)d_in[4];
  const float* b1  = (const float*)d_in[5];
  const float* W2  = (const float*)d_in[6];
  const float* b2  = (const float*)d_in[7];
  const float* W3  = (const float*)d_in[8];
  const float* b3  = (const float*)d_in[9];
  float* out = (float*)d_out;

  char* wsp = (char*)d_ws;
  auto alloc = [&](size_t bytes) {
    char* p = wsp;
    wsp += (bytes + 255) & ~(size_t)255;
    return p;
  };
  short*    Pp_h  = (short*)alloc(16384ull * 1024 * 2);     // [P;H] split planes
  short*    Pp_l  = (short*)alloc(16384ull * 1024 * 2);
  _Float16* Cat16 = (_Float16*)alloc(16384ull * 2048 * 2);  // [P|betas ; H|alphas]
  _Float16* PHbT  = (_Float16*)alloc(64ull * 1024 * 256 * 2); // P^T,H^T fp16
  short*    Fbuf  = (short*)alloc(32ull * 1024 * 1024 * 2);   // F split planes
  short*    WFT_h = (short*)alloc(1024ull * 1024 * 2);
  short*    WFT_l = (short*)alloc(1024ull * 1024 * 2);
  _Float16* WGT16 = (_Float16*)alloc(2048ull * 2048 * 2);
  float*    eijs  = (float*)alloc(32ull * 256 * 256 * 4);   // NB: contiguous with
  float*    agg   = (float*)alloc(32ull * 4096 * 4);        //     agg (one zero)
  _Float16* attn  = (_Float16*)alloc(32ull * 256 * 256 * 2);
  _Float16* attnT = (_Float16*)alloc(32ull * 256 * 256 * 2);

  short* F_h = Fbuf;
  short* F_l = Fbuf + 16384ull * 1024;
  _Float16* PbT = PHbT;
  _Float16* HbT = PHbT + 32ull * 1024 * 256;
  // classifier scratch aliases Pp planes (dead after the F GEMM)
  float* c1p = (float*)Pp_h;                 // [32][32][2048] = 8 MB
  float* c2p = c1p + 32ull * 32 * 2048;      // 8 MB
  float* a1f = c2p + 32ull * 32 * 2048;      // [32][2048] fp32

  // 1. upfront zero (eijs+agg contiguous), input fusion, weight transposes
  zero_f32<<<8704, 256, 0, stream>>>(eijs, 32 * 256 * 256 + 32 * 4096);
  fused_in<<<dim3(32, 8, 64), 256, 0, stream>>>(P, H, Pp_h, Pp_l, Cat16, PHbT);
  transpose_split<<<dim3(32, 32, 1), 256, 0, stream>>>(W_F, WFT_h, WFT_l, 1024, 1024);
  transpose_f16<<<dim3(64, 64, 1), 256, 0, stream>>>(W_G, WGT16, 2048, 2048);

  // 2. F = tanh([P;H] @ W_F), split bf16x3 (sync staging)
  gemm_nt_split<1, 1><<<dim3(128, 8, 1), 256, 0, stream>>>(
      Pp_h, Pp_l, 1024, 0, WFT_h, WFT_l, 1024, 0,
      F_h, F_l, 1024, 0, 16384, 1024, 1);

  // 3. scores E[z] = F_p[z] @ F_h[z]^T, split bf16x3, split-K x4 (atomic fp32)
  gemm_nt_split<0, 0><<<dim3(2, 2, 128), 256, 0, stream>>>(
      F_h, F_l, 1024, 256 * 1024,
      F_h + 8192ull * 1024, F_l + 8192ull * 1024, 1024, 256 * 1024,
      eijs, nullptr, 256, 65536, 256, 1024, 4);

  // 4. softmax -> fp16 attn; attn^T
  softmax_rows<<<2048, 256, 0, stream>>>(eijs, attn);
  transpose_b2b<<<dim3(8, 8, 32), 256, 0, stream>>>(
      (const short*)attn, (short*)attnT, 256, 256, 65536, 65536);

  // 5. betas = attn @ H -> Cat1 right; alphas = attn^T @ P -> Cat2 right (fp16)
  gemm_f16<1><<<dim3(2, 8, 32), 256, 0, stream>>>(
      attn, 256, 65536, HbT, 256, 1024 * 256,
      Cat16 + 1024, 2048, 256 * 2048, 256, nullptr);
  gemm_f16<1><<<dim3(2, 8, 32), 256, 0, stream>>>(
      attnT, 256, 65536, PbT, 256, 1024 * 256,
      Cat16 + 8192ull * 2048 + 1024, 2048, 256 * 2048, 256, nullptr);

  // 6. V = tanh(Cat @ W_G) fused column-sum -> agg (fp16, BK=64)
  gemm_f16<2><<<dim3(128, 16, 1), 256, 0, stream>>>(
      Cat16, 2048, 0, WGT16, 2048, 0, nullptr, 0, 0, 2048, agg);

  // 7. classifier: fp32 skinny GEMMs (k-sliced partials) + reduce epilogues
  skinny_gemm<<<dim3(8, 32), 256, 0, stream>>>(agg, 4096, W1, 2048, 128, c1p);
  reduce_bias_tanh<<<256, 256, 0, stream>>>(c1p, b1, a1f, 32 * 2048, 32);
  skinny_gemm<<<dim3(8, 32), 256, 0, stream>>>(a1f, 2048, W2, 2048, 64, c2p);
  logits_red<<<32, 256, 0, stream>>>(c2p, b2, W3, b3, out, 32);
}

// Round 7
// 800.988 us; speedup vs baseline: 1.0183x; 1.0183x over previous
//
#include <hip/hip_runtime.h>
#include <hip/hip_bf16.h>
#include <stdint.h>

// Shapes: B=32, L=256, D=1024, ALIGN=1024, FF=2048, NC=3
// Precision plan:
//  - F proj, E scores: bf16x3 split (~fp32) -- the softmax-sensitive path
//  - attn, betas/alphas, V=tanh(Cat@W_G): fp16 single (store rounding dominates)
//  - classifier: fp32 VALU skinny GEMMs (exact, M=32 is tiny)
// R7 bisect: R4 input stage (conv_in + transpose_f16_ph, vectorized stores)
// + skinny classifier. Only ONE change vs the known-643us R4 baseline.

typedef __attribute__((ext_vector_type(8))) short    short8_t;   // 8 bf16
typedef __attribute__((ext_vector_type(4))) float    float4_t;
typedef __attribute__((ext_vector_type(8))) _Float16 half8_t;
typedef __attribute__((ext_vector_type(4))) _Float16 half4_t;

#define DEVI static __device__ __forceinline__

DEVI short f2bf(float f) {
  union { float f; unsigned u; } v; v.f = f;
  unsigned r = v.u + 0x7fffu + ((v.u >> 16) & 1u);   // RNE
  return (short)(r >> 16);
}
DEVI float bf2f(short s) {
  union { unsigned u; float f; } v;
  v.u = ((unsigned)(unsigned short)s) << 16;
  return v.f;
}
DEVI void split2(float x, short& hi, short& lo) {
  hi = f2bf(x);
  lo = f2bf(x - bf2f(hi));
}
DEVI float fast_tanh(float x) {
  float e = __expf(2.0f * x);
  return 1.0f - 2.0f / (e + 1.0f);
}
DEVI void gload16(const void* g, void* l) {
  // async global->LDS, 16B/lane; LDS dest = wave-uniform base + lane*16
  __builtin_amdgcn_global_load_lds(
      (const __attribute__((address_space(1))) void*)g,
      (__attribute__((address_space(3))) void*)l, 16, 0, 0);
}

// ---------------------------------------------------------------------------
// Split-bf16 NT GEMM (A=Ah+Al, B=Bh+Bl), 128x128 tile, BK=32, 4 waves,
// 3 MFMAs per product (hh,hl,lh). SYNC staging (VGPR roundtrip, [40] pad).
// blockIdx.z = batch*kslices + kslice.
// OUT_MODE: 0 = fp32 atomicAdd (split-K; C pre-zeroed), 1 = split bf16 store.
// ---------------------------------------------------------------------------
template <int DO_TANH, int OUT_MODE>
__global__ __launch_bounds__(256) void gemm_nt_split(
    const short* __restrict__ Ah, const short* __restrict__ Al, int lda, long sA,
    const short* __restrict__ Bh, const short* __restrict__ Bl, int ldb, long sB,
    void* __restrict__ Ch, void* __restrict__ Cl, int ldc, long sC,
    int M, int K, int kslices)
{
  __shared__ __align__(16) short Ash[128][40];
  __shared__ __align__(16) short Asl[128][40];
  __shared__ __align__(16) short Bsh[128][40];
  __shared__ __align__(16) short Bsl[128][40];

  const int z  = blockIdx.z;
  const int zb = z / kslices;
  const int zk = z - zb * kslices;
  const int Ksub = K / kslices;
  const int kbeg = zk * Ksub, kend = kbeg + Ksub;

  Ah += (size_t)zb * sA;  Al += (size_t)zb * sA;
  Bh += (size_t)zb * sB;  Bl += (size_t)zb * sB;

  const int row0 = blockIdx.x * 128;
  const int col0 = blockIdx.y * 128;

  const int t    = threadIdx.x;
  const int lane = t & 63;
  const int wave = t >> 6;
  const int wr = wave >> 1, wc = wave & 1;
  const int m15 = lane & 15, q = lane >> 4;

  float4_t acc[4][4];
#pragma unroll
  for (int i = 0; i < 4; ++i)
#pragma unroll
    for (int j = 0; j < 4; ++j) acc[i][j] = (float4_t)0.0f;

  for (int k0 = kbeg; k0 < kend; k0 += 32) {
#pragma unroll
    for (int i = 0; i < 2; ++i) {
      int c  = t + 256 * i;       // 0..511
      int r  = c >> 2;            // 0..127
      int kc = (c & 3) << 3;      // 0,8,16,24
      size_t ao = (size_t)(row0 + r) * lda + k0 + kc;
      size_t bo = (size_t)(col0 + r) * ldb + k0 + kc;
      *(int4*)(&Ash[r][kc]) = *(const int4*)(Ah + ao);
      *(int4*)(&Asl[r][kc]) = *(const int4*)(Al + ao);
      *(int4*)(&Bsh[r][kc]) = *(const int4*)(Bh + bo);
      *(int4*)(&Bsl[r][kc]) = *(const int4*)(Bl + bo);
    }
    __syncthreads();

    short8_t ah[4], al[4];
#pragma unroll
    for (int i = 0; i < 4; ++i) {
      ah[i] = *(const short8_t*)(&Ash[wr * 64 + i * 16 + m15][q * 8]);
      al[i] = *(const short8_t*)(&Asl[wr * 64 + i * 16 + m15][q * 8]);
    }
#pragma unroll
    for (int j = 0; j < 4; ++j) {
      short8_t bh = *(const short8_t*)(&Bsh[wc * 64 + j * 16 + m15][q * 8]);
      short8_t bl = *(const short8_t*)(&Bsl[wc * 64 + j * 16 + m15][q * 8]);
#pragma unroll
      for (int i = 0; i < 4; ++i) {
        acc[i][j] = __builtin_amdgcn_mfma_f32_16x16x32_bf16(ah[i], bh, acc[i][j], 0, 0, 0);
        acc[i][j] = __builtin_amdgcn_mfma_f32_16x16x32_bf16(ah[i], bl, acc[i][j], 0, 0, 0);
        acc[i][j] = __builtin_amdgcn_mfma_f32_16x16x32_bf16(al[i], bh, acc[i][j], 0, 0, 0);
      }
    }
    __syncthreads();
  }

  short* Chs = (short*)Ch + (size_t)zb * sC;
  short* Cls = (short*)Cl + (size_t)zb * sC;
  float* Cf  = (float*)Ch + (size_t)zb * sC;
#pragma unroll
  for (int i = 0; i < 4; ++i) {
#pragma unroll
    for (int r = 0; r < 4; ++r) {
      int gm = row0 + wr * 64 + i * 16 + q * 4 + r;
      if (gm < M) {
#pragma unroll
        for (int j = 0; j < 4; ++j) {
          int gn = col0 + wc * 64 + j * 16 + m15;
          float v = acc[i][j][r];
          if (DO_TANH) v = fast_tanh(v);
          if (OUT_MODE == 0) {
            atomicAdd(&Cf[(size_t)gm * ldc + gn], v);
          } else {
            short hi, lo; split2(v, hi, lo);
            Chs[(size_t)gm * ldc + gn] = hi;
            Cls[(size_t)gm * ldc + gn] = lo;
          }
        }
      }
    }
  }
}

// ---------------------------------------------------------------------------
// fp16 single-pass NT GEMM, BK=64, async staging, XOR-swizzled LDS.
// MODE 1: fp16 store (betas/alphas; batched via blockIdx.z)
// MODE 2: tanh + column-sum -> agg (V: 16384 rows = [Cat1;Cat2], agg[32][4096])
// ---------------------------------------------------------------------------
template <int MODE>
__global__ __launch_bounds__(256) void gemm_f16(
    const _Float16* __restrict__ A, int lda, long sA,
    const _Float16* __restrict__ B, int ldb, long sB,
    _Float16* __restrict__ C, int ldc, long sC,
    int K, float* __restrict__ agg)
{
  __shared__ __align__(16) _Float16 As[2 * 128 * 32];
  __shared__ __align__(16) _Float16 Bs[2 * 128 * 32];

  const int z = blockIdx.z;
  A += (size_t)z * sA;
  B += (size_t)z * sB;

  const int row0 = blockIdx.x * 128;
  const int col0 = blockIdx.y * 128;
  const int t = threadIdx.x, lane = t & 63, wave = t >> 6;
  const int wr = wave >> 1, wc = wave & 1;
  const int m15 = lane & 15, q = lane >> 4;

  const int srow = wave * 32 + (lane >> 2);
  const int cg   = ((lane & 3) ^ ((lane >> 3) & 3)) * 8;
  const _Float16* gA0 = A + (size_t)(row0 + srow) * lda + cg;
  const _Float16* gA1 = gA0 + (size_t)16 * lda;
  const _Float16* gB0 = B + (size_t)(col0 + srow) * ldb + cg;
  const _Float16* gB1 = gB0 + (size_t)16 * ldb;
  const _Float16* gA0b = gA0 + 32;
  const _Float16* gA1b = gA1 + 32;
  const _Float16* gB0b = gB0 + 32;
  const _Float16* gB1b = gB1 + 32;
  _Float16* lA0  = &As[(wave * 32) * 32];
  _Float16* lA1  = &As[(wave * 32 + 16) * 32];
  _Float16* lB0  = &Bs[(wave * 32) * 32];
  _Float16* lB1  = &Bs[(wave * 32 + 16) * 32];
  _Float16* lA0b = lA0 + 4096;
  _Float16* lA1b = lA1 + 4096;
  _Float16* lB0b = lB0 + 4096;
  _Float16* lB1b = lB1 + 4096;

  const int fs = (q ^ ((m15 >> 1) & 3)) * 8;
  int aoff[4], boff[4];
#pragma unroll
  for (int i = 0; i < 4; ++i) {
    aoff[i] = (wr * 64 + i * 16 + m15) * 32 + fs;
    boff[i] = (wc * 64 + i * 16 + m15) * 32 + fs;
  }

  float4_t acc[4][4];
#pragma unroll
  for (int i = 0; i < 4; ++i)
#pragma unroll
    for (int j = 0; j < 4; ++j) acc[i][j] = (float4_t)0.0f;

  for (int k0 = 0; k0 < K; k0 += 64) {
    gload16(gA0, lA0);  gload16(gA1, lA1);
    gload16(gB0, lB0);  gload16(gB1, lB1);
    gload16(gA0b, lA0b); gload16(gA1b, lA1b);
    gload16(gB0b, lB0b); gload16(gB1b, lB1b);
    gA0 += 64; gA1 += 64; gB0 += 64; gB1 += 64;
    gA0b += 64; gA1b += 64; gB0b += 64; gB1b += 64;
    __syncthreads();

#pragma unroll
    for (int h = 0; h < 2; ++h) {
      half8_t af[4], bfr[4];
#pragma unroll
      for (int i = 0; i < 4; ++i) af[i]  = *(const half8_t*)&As[h * 4096 + aoff[i]];
#pragma unroll
      for (int j = 0; j < 4; ++j) bfr[j] = *(const half8_t*)&Bs[h * 4096 + boff[j]];
#pragma unroll
      for (int i = 0; i < 4; ++i)
#pragma unroll
        for (int j = 0; j < 4; ++j)
          acc[i][j] = __builtin_amdgcn_mfma_f32_16x16x32_f16(af[i], bfr[j], acc[i][j], 0, 0, 0);
    }
    __syncthreads();
  }

  if (MODE == 2) {
    const int half_ = row0 >= 8192;
    const int b     = (row0 & 8191) >> 8;
#pragma unroll
    for (int j = 0; j < 4; ++j) {
      float s = 0.0f;
#pragma unroll
      for (int i = 0; i < 4; ++i)
#pragma unroll
        for (int r = 0; r < 4; ++r) s += fast_tanh(acc[i][j][r]);
      s += __shfl_xor(s, 16);
      s += __shfl_xor(s, 32);
      if (q == 0) {
        int col = col0 + wc * 64 + j * 16 + m15;
        atomicAdd(&agg[(size_t)b * 4096 + half_ * 2048 + col], s);
      }
    }
  } else {
    _Float16* Cp = C + (size_t)z * sC;
#pragma unroll
    for (int i = 0; i < 4; ++i)
#pragma unroll
      for (int r = 0; r < 4; ++r) {
        int gm = row0 + wr * 64 + i * 16 + q * 4 + r;
#pragma unroll
        for (int j = 0; j < 4; ++j) {
          int gn = col0 + wc * 64 + j * 16 + m15;
          Cp[(size_t)gm * ldc + gn] = (_Float16)acc[i][j][r];
        }
      }
  }
}

// --- input conv: fp32 [P;H] -> split bf16 planes + fp16 Cat left halves ---
// grid (8192, 1, 2): z = 0 -> P, z = 1 -> H. Vectorized loads/stores.
__global__ __launch_bounds__(256) void conv_in(
    const float* __restrict__ P, const float* __restrict__ Hh,
    short* __restrict__ oh, short* __restrict__ ol, _Float16* __restrict__ cat)
{
  const int zz = blockIdx.z;
  const float* in = zz ? Hh : P;
  oh  += (size_t)zz * 8192 * 1024;
  ol  += (size_t)zz * 8192 * 1024;
  cat += (size_t)zz * 8192 * 2048;
  size_t i = ((size_t)blockIdx.x * 256 + threadIdx.x) * 4;
  float4 v = *(const float4*)&in[i];
  short4 h, l;
  split2(v.x, h.x, l.x); split2(v.y, h.y, l.y);
  split2(v.z, h.z, l.z); split2(v.w, h.w, l.w);
  *(short4*)&oh[i] = h;
  *(short4*)&ol[i] = l;
  size_t row = i >> 10;
  int col    = (int)(i & 1023);
  half4_t c16;
  c16.x = (_Float16)v.x; c16.y = (_Float16)v.y;
  c16.z = (_Float16)v.z; c16.w = (_Float16)v.w;
  *(half4_t*)&cat[row * 2048 + col] = c16;
}

// --- batched fp32 -> fp16 transpose of P (z<32) and H (z>=32): out[z][c][r] ---
__global__ __launch_bounds__(256) void transpose_f16_ph(
    const float* __restrict__ P, const float* __restrict__ Hh,
    _Float16* __restrict__ out)
{
  __shared__ float tile[32][33];
  const int zz = blockIdx.z;
  const float* in = (zz < 32 ? P : Hh) + (size_t)(zz & 31) * (256 * 1024);
  _Float16* o = out + (size_t)zz * (1024 * 256);
  const int tx = threadIdx.x & 31, ty = threadIdx.x >> 5;
  const int c0 = blockIdx.x * 32, r0 = blockIdx.y * 32;   // c over 1024, r over 256
#pragma unroll
  for (int i = 0; i < 4; ++i) {
    int r = ty + i * 8;
    tile[r][tx] = in[(size_t)(r0 + r) * 1024 + c0 + tx];
  }
  __syncthreads();
#pragma unroll
  for (int i = 0; i < 4; ++i) {
    int cc = ty + i * 8;
    o[(size_t)(c0 + cc) * 256 + r0 + tx] = (_Float16)tile[tx][cc];
  }
}

// --- fp32 -> split bf16 transpose: out[c][r] ---
__global__ __launch_bounds__(256) void transpose_split(
    const float* __restrict__ in, short* __restrict__ oh, short* __restrict__ ol,
    int R, int C)
{
  __shared__ float tile[32][33];
  const int tx = threadIdx.x & 31, ty = threadIdx.x >> 5;
  const int c0 = blockIdx.x * 32, r0 = blockIdx.y * 32;
#pragma unroll
  for (int i = 0; i < 4; ++i) {
    int r = ty + i * 8;
    tile[r][tx] = in[(size_t)(r0 + r) * C + c0 + tx];
  }
  __syncthreads();
#pragma unroll
  for (int i = 0; i < 4; ++i) {
    int cc = ty + i * 8;
    float v = tile[tx][cc];
    short hi, lo; split2(v, hi, lo);
    size_t o = (size_t)(c0 + cc) * R + r0 + tx;
    oh[o] = hi;
    ol[o] = lo;
  }
}

// --- fp32 -> fp16 transpose: out[c][r] ---
__global__ __launch_bounds__(256) void transpose_f16(
    const float* __restrict__ in, _Float16* __restrict__ out, int R, int C)
{
  __shared__ float tile[32][33];
  const int tx = threadIdx.x & 31, ty = threadIdx.x >> 5;
  const int c0 = blockIdx.x * 32, r0 = blockIdx.y * 32;
#pragma unroll
  for (int i = 0; i < 4; ++i) {
    int r = ty + i * 8;
    tile[r][tx] = in[(size_t)(r0 + r) * C + c0 + tx];
  }
  __syncthreads();
#pragma unroll
  for (int i = 0; i < 4; ++i) {
    int cc = ty + i * 8;
    out[(size_t)(c0 + cc) * R + r0 + tx] = (_Float16)tile[tx][cc];
  }
}

// --- fp16 [256x256] batched transpose (attn -> attnT), bit-copy as short ---
__global__ __launch_bounds__(256) void transpose_b2b(
    const short* __restrict__ in, short* __restrict__ out,
    int R, int C, long sIn, long sOut)
{
  __shared__ short tile[32][33];
  in  += (size_t)blockIdx.z * sIn;
  out += (size_t)blockIdx.z * sOut;
  const int tx = threadIdx.x & 31, ty = threadIdx.x >> 5;
  const int c0 = blockIdx.x * 32, r0 = blockIdx.y * 32;
#pragma unroll
  for (int i = 0; i < 4; ++i) {
    int r = ty + i * 8;
    tile[r][tx] = in[(size_t)(r0 + r) * C + c0 + tx];
  }
  __syncthreads();
#pragma unroll
  for (int i = 0; i < 4; ++i) {
    int cc = ty + i * 8;
    out[(size_t)(c0 + cc) * R + r0 + tx] = tile[tx][cc];
  }
}

__global__ __launch_bounds__(256) void zero_f32(float* __restrict__ p, int n)
{
  int i = blockIdx.x * 256 + threadIdx.x;
  if (i < n) p[i] = 0.0f;
}

// --- softmax over rows of 256 (one wave per row), fp32 -> fp16 ---
__global__ __launch_bounds__(256) void softmax_rows(
    const float* __restrict__ e, _Float16* __restrict__ attn)
{
  const int row  = blockIdx.x * 4 + (threadIdx.x >> 6);
  const int lane = threadIdx.x & 63;
  const float4 v = *(const float4*)&e[(size_t)row * 256 + lane * 4];
  float m = fmaxf(fmaxf(v.x, v.y), fmaxf(v.z, v.w));
#pragma unroll
  for (int off = 32; off; off >>= 1) m = fmaxf(m, __shfl_xor(m, off));
  float e0 = __expf(v.x - m), e1 = __expf(v.y - m);
  float e2 = __expf(v.z - m), e3 = __expf(v.w - m);
  float s = e0 + e1 + e2 + e3;
#pragma unroll
  for (int off = 32; off; off >>= 1) s += __shfl_xor(s, off);
  float inv = 1.0f / s;
  half4_t o;
  o.x = (_Float16)(e0 * inv); o.y = (_Float16)(e1 * inv);
  o.z = (_Float16)(e2 * inv); o.w = (_Float16)(e3 * inv);
  *(half4_t*)&attn[(size_t)row * 256 + lane * 4] = o;
}

// --- fp32 skinny GEMM: part[ks][32][N] = A[32][KA] @ W[KA][N] (k-slice ks) ---
// A reads are wave-uniform -> scalar loads; W reads coalesced over n.
__global__ __launch_bounds__(256) void skinny_gemm(
    const float* __restrict__ A, int lda,
    const float* __restrict__ W, int N, int Kslice,
    float* __restrict__ part)
{
  const int n  = blockIdx.x * 256 + threadIdx.x;
  const int k0 = blockIdx.y * Kslice;
  float acc[32];
#pragma unroll
  for (int m = 0; m < 32; ++m) acc[m] = 0.0f;
  for (int k = k0; k < k0 + Kslice; ++k) {
    float w = W[(size_t)k * N + n];
#pragma unroll
    for (int m = 0; m < 32; ++m)
      acc[m] = fmaf(A[m * lda + k], w, acc[m]);
  }
  float* pp = part + (size_t)blockIdx.y * 32 * N;
#pragma unroll
  for (int m = 0; m < 32; ++m) pp[(size_t)m * N + n] = acc[m];
}

// --- out[i] = tanh(bias[i & 2047] + sum_s part[s*n + i]) ---
__global__ __launch_bounds__(256) void reduce_bias_tanh(
    const float* __restrict__ part, const float* __restrict__ bias,
    float* __restrict__ outp, int n, int slices)
{
  int i = blockIdx.x * 256 + threadIdx.x;
  if (i >= n) return;
  float s = bias[i & 2047];
  for (int sl = 0; sl < slices; ++sl) s += part[(size_t)sl * n + i];
  outp[i] = fast_tanh(s);
}

// --- logits: block b: out[b] = tanh(sum_s c2p[s][b] + b2) @ W3 + b3 ---
__global__ __launch_bounds__(256) void logits_red(
    const float* __restrict__ part, const float* __restrict__ b2,
    const float* __restrict__ W3, const float* __restrict__ b3,
    float* __restrict__ out, int slices)
{
  const int b = blockIdx.x, t = threadIdx.x;
  float p0 = 0.f, p1 = 0.f, p2 = 0.f;
  for (int k = t; k < 2048; k += 256) {
    float a = b2[k];
    for (int sl = 0; sl < slices; ++sl)
      a += part[((size_t)sl * 32 + b) * 2048 + k];
    a = fast_tanh(a);
    p0 += a * W3[k * 3 + 0];
    p1 += a * W3[k * 3 + 1];
    p2 += a * W3[k * 3 + 2];
  }
#pragma unroll
  for (int off = 32; off; off >>= 1) {
    p0 += __shfl_xor(p0, off);
    p1 += __shfl_xor(p1, off);
    p2 += __shfl_xor(p2, off);
  }
  __shared__ float red[4][3];
  if ((t & 63) == 0) {
    red[t >> 6][0] = p0; red[t >> 6][1] = p1; red[t >> 6][2] = p2;
  }
  __syncthreads();
  if (t < 3) out[b * 3 + t] = b3[t] + red[0][t] + red[1][t] + red[2][t] + red[3][t];
}

extern "C" void kernel_launch(void* const* d_in, const int* in_sizes, int n_in,
                              void* d_out, int out_size, void* d_ws, size_t ws_size,
                              hipStream_t stream) {
  (void)in_sizes; (void)n_in; (void)out_size; (void)ws_size;
  const float* P   = (const float*)d_in[0];
  const float* H   = (const float*)d_in[1];
  const float* W_F = (const float*)d_in[2];
  const float* W_G = (const float*)d_in[3];
  const float* W1  = (const float*)d_in[4];
  const float* b1  = (const float*)d_in[5];
  const float* W2  = (const float*)d_in[6];
  const float* b2  = (const float*)d_in[7];
  const float* W3  = (const float*)d_in[8];
  const float* b3  = (const float*)d_in[9];
  float* out = (float*)d_out;

  char* wsp = (char*)d_ws;
  auto alloc = [&](size_t bytes) {
    char* p = wsp;
    wsp += (bytes + 255) & ~(size_t)255;
    return p;
  };
  short*    Pp_h  = (short*)alloc(16384ull * 1024 * 2);     // [P;H] split planes
  short*    Pp_l  = (short*)alloc(16384ull * 1024 * 2);
  _Float16* Cat16 = (_Float16*)alloc(16384ull * 2048 * 2);  // [P|betas ; H|alphas]
  _Float16* PHbT  = (_Float16*)alloc(64ull * 1024 * 256 * 2); // P^T,H^T fp16
  short*    Fbuf  = (short*)alloc(32ull * 1024 * 1024 * 2);   // F split planes
  short*    WFT_h = (short*)alloc(1024ull * 1024 * 2);
  short*    WFT_l = (short*)alloc(1024ull * 1024 * 2);
  _Float16* WGT16 = (_Float16*)alloc(2048ull * 2048 * 2);
  float*    eijs  = (float*)alloc(32ull * 256 * 256 * 4);   // NB: contiguous with
  float*    agg   = (float*)alloc(32ull * 4096 * 4);        //     agg (one zero)
  _Float16* attn  = (_Float16*)alloc(32ull * 256 * 256 * 2);
  _Float16* attnT = (_Float16*)alloc(32ull * 256 * 256 * 2);

  short* F_h = Fbuf;
  short* F_l = Fbuf + 16384ull * 1024;
  _Float16* PbT = PHbT;
  _Float16* HbT = PHbT + 32ull * 1024 * 256;
  // classifier scratch aliases Pp planes (dead after the F GEMM)
  float* c1p = (float*)Pp_h;                 // [32][32][2048] = 8 MB
  float* c2p = c1p + 32ull * 32 * 2048;      // 8 MB
  float* a1f = c2p + 32ull * 32 * 2048;      // [32][2048] fp32

  // 1. upfront zero (eijs+agg contiguous), input conversions, weight transposes
  zero_f32<<<8704, 256, 0, stream>>>(eijs, 32 * 256 * 256 + 32 * 4096);
  conv_in<<<dim3(8192, 1, 2), 256, 0, stream>>>(P, H, Pp_h, Pp_l, Cat16);
  transpose_f16_ph<<<dim3(32, 8, 64), 256, 0, stream>>>(P, H, PHbT);
  transpose_split<<<dim3(32, 32, 1), 256, 0, stream>>>(W_F, WFT_h, WFT_l, 1024, 1024);
  transpose_f16<<<dim3(64, 64, 1), 256, 0, stream>>>(W_G, WGT16, 2048, 2048);

  // 2. F = tanh([P;H] @ W_F), split bf16x3 (sync staging)
  gemm_nt_split<1, 1><<<dim3(128, 8, 1), 256, 0, stream>>>(
      Pp_h, Pp_l, 1024, 0, WFT_h, WFT_l, 1024, 0,
      F_h, F_l, 1024, 0, 16384, 1024, 1);

  // 3. scores E[z] = F_p[z] @ F_h[z]^T, split bf16x3, split-K x4 (atomic fp32)
  gemm_nt_split<0, 0><<<dim3(2, 2, 128), 256, 0, stream>>>(
      F_h, F_l, 1024, 256 * 1024,
      F_h + 8192ull * 1024, F_l + 8192ull * 1024, 1024, 256 * 1024,
      eijs, nullptr, 256, 65536, 256, 1024, 4);

  // 4. softmax -> fp16 attn; attn^T
  softmax_rows<<<2048, 256, 0, stream>>>(eijs, attn);
  transpose_b2b<<<dim3(8, 8, 32), 256, 0, stream>>>(
      (const short*)attn, (short*)attnT, 256, 256, 65536, 65536);

  // 5. betas = attn @ H -> Cat1 right; alphas = attn^T @ P -> Cat2 right (fp16)
  gemm_f16<1><<<dim3(2, 8, 32), 256, 0, stream>>>(
      attn, 256, 65536, HbT, 256, 1024 * 256,
      Cat16 + 1024, 2048, 256 * 2048, 256, nullptr);
  gemm_f16<1><<<dim3(2, 8, 32), 256, 0, stream>>>(
      attnT, 256, 65536, PbT, 256, 1024 * 256,
      Cat16 + 8192ull * 2048 + 1024, 2048, 256 * 2048, 256, nullptr);

  // 6. V = tanh(Cat @ W_G) fused column-sum -> agg (fp16, BK=64)
  gemm_f16<2><<<dim3(128, 16, 1), 256, 0, stream>>>(
      Cat16, 2048, 0, WGT16, 2048, 0, nullptr, 0, 0, 2048, agg);

  // 7. classifier: fp32 skinny GEMMs (k-sliced partials) + reduce epilogues
  skinny_gemm<<<dim3(8, 32), 256, 0, stream>>>(agg, 4096, W1, 2048, 128, c1p);
  reduce_bias_tanh<<<256, 256, 0, stream>>>(c1p, b1, a1f, 32 * 2048, 32);
  skinny_gemm<<<dim3(8, 32), 256, 0, stream>>>(a1f, 2048, W2, 2048, 64, c2p);
  logits_red<<<32, 256, 0, stream>>>(c2p, b2, W3, b3, out, 32);
}

// Round 8
// 665.405 us; speedup vs baseline: 1.2258x; 1.2038x over previous
//
#include <hip/hip_runtime.h>
#include <hip/hip_bf16.h>
#include <stdint.h>

// Shapes: B=32, L=256, D=1024, ALIGN=1024, FF=2048, NC=3
// Precision plan:
//  - F proj, E scores: bf16x3 split (~fp32) -- the softmax-sensitive path
//  - attn, betas/alphas, V=tanh(Cat@W_G): fp16 single (store rounding dominates)
//  - classifier: fp32 skinny GEMMs, LATENCY-TOLERANT version:
//    LDS-staged A (inner loop = streaming W loads only, unroll-8 MLP),
//    compile-time-unrolled slice reductions. R5-R7's version was
//    latency-serialized (1 wave/SIMD + rolled runtime-bound loops): +160us.
// Everything else is the R4 643us artifact, verbatim.

typedef __attribute__((ext_vector_type(8))) short    short8_t;   // 8 bf16
typedef __attribute__((ext_vector_type(4))) float    float4_t;
typedef __attribute__((ext_vector_type(8))) _Float16 half8_t;
typedef __attribute__((ext_vector_type(4))) _Float16 half4_t;

#define DEVI static __device__ __forceinline__

DEVI short f2bf(float f) {
  union { float f; unsigned u; } v; v.f = f;
  unsigned r = v.u + 0x7fffu + ((v.u >> 16) & 1u);   // RNE
  return (short)(r >> 16);
}
DEVI float bf2f(short s) {
  union { unsigned u; float f; } v;
  v.u = ((unsigned)(unsigned short)s) << 16;
  return v.f;
}
DEVI void split2(float x, short& hi, short& lo) {
  hi = f2bf(x);
  lo = f2bf(x - bf2f(hi));
}
DEVI float fast_tanh(float x) {
  float e = __expf(2.0f * x);
  return 1.0f - 2.0f / (e + 1.0f);
}
DEVI void gload16(const void* g, void* l) {
  __builtin_amdgcn_global_load_lds(
      (const __attribute__((address_space(1))) void*)g,
      (__attribute__((address_space(3))) void*)l, 16, 0, 0);
}

// ---------------------------------------------------------------------------
// Split-bf16 NT GEMM (A=Ah+Al, B=Bh+Bl), 128x128 tile, BK=32, 4 waves,
// 3 MFMAs per product (hh,hl,lh). SYNC staging (VGPR roundtrip, [40] pad).
// OUT_MODE: 0 = fp32 atomicAdd (split-K; C pre-zeroed), 1 = split bf16 store.
// ---------------------------------------------------------------------------
template <int DO_TANH, int OUT_MODE>
__global__ __launch_bounds__(256) void gemm_nt_split(
    const short* __restrict__ Ah, const short* __restrict__ Al, int lda, long sA,
    const short* __restrict__ Bh, const short* __restrict__ Bl, int ldb, long sB,
    void* __restrict__ Ch, void* __restrict__ Cl, int ldc, long sC,
    int M, int K, int kslices)
{
  __shared__ __align__(16) short Ash[128][40];
  __shared__ __align__(16) short Asl[128][40];
  __shared__ __align__(16) short Bsh[128][40];
  __shared__ __align__(16) short Bsl[128][40];

  const int z  = blockIdx.z;
  const int zb = z / kslices;
  const int zk = z - zb * kslices;
  const int Ksub = K / kslices;
  const int kbeg = zk * Ksub, kend = kbeg + Ksub;

  Ah += (size_t)zb * sA;  Al += (size_t)zb * sA;
  Bh += (size_t)zb * sB;  Bl += (size_t)zb * sB;

  const int row0 = blockIdx.x * 128;
  const int col0 = blockIdx.y * 128;

  const int t    = threadIdx.x;
  const int lane = t & 63;
  const int wave = t >> 6;
  const int wr = wave >> 1, wc = wave & 1;
  const int m15 = lane & 15, q = lane >> 4;

  float4_t acc[4][4];
#pragma unroll
  for (int i = 0; i < 4; ++i)
#pragma unroll
    for (int j = 0; j < 4; ++j) acc[i][j] = (float4_t)0.0f;

  for (int k0 = kbeg; k0 < kend; k0 += 32) {
#pragma unroll
    for (int i = 0; i < 2; ++i) {
      int c  = t + 256 * i;       // 0..511
      int r  = c >> 2;            // 0..127
      int kc = (c & 3) << 3;      // 0,8,16,24
      size_t ao = (size_t)(row0 + r) * lda + k0 + kc;
      size_t bo = (size_t)(col0 + r) * ldb + k0 + kc;
      *(int4*)(&Ash[r][kc]) = *(const int4*)(Ah + ao);
      *(int4*)(&Asl[r][kc]) = *(const int4*)(Al + ao);
      *(int4*)(&Bsh[r][kc]) = *(const int4*)(Bh + bo);
      *(int4*)(&Bsl[r][kc]) = *(const int4*)(Bl + bo);
    }
    __syncthreads();

    short8_t ah[4], al[4];
#pragma unroll
    for (int i = 0; i < 4; ++i) {
      ah[i] = *(const short8_t*)(&Ash[wr * 64 + i * 16 + m15][q * 8]);
      al[i] = *(const short8_t*)(&Asl[wr * 64 + i * 16 + m15][q * 8]);
    }
#pragma unroll
    for (int j = 0; j < 4; ++j) {
      short8_t bh = *(const short8_t*)(&Bsh[wc * 64 + j * 16 + m15][q * 8]);
      short8_t bl = *(const short8_t*)(&Bsl[wc * 64 + j * 16 + m15][q * 8]);
#pragma unroll
      for (int i = 0; i < 4; ++i) {
        acc[i][j] = __builtin_amdgcn_mfma_f32_16x16x32_bf16(ah[i], bh, acc[i][j], 0, 0, 0);
        acc[i][j] = __builtin_amdgcn_mfma_f32_16x16x32_bf16(ah[i], bl, acc[i][j], 0, 0, 0);
        acc[i][j] = __builtin_amdgcn_mfma_f32_16x16x32_bf16(al[i], bh, acc[i][j], 0, 0, 0);
      }
    }
    __syncthreads();
  }

  short* Chs = (short*)Ch + (size_t)zb * sC;
  short* Cls = (short*)Cl + (size_t)zb * sC;
  float* Cf  = (float*)Ch + (size_t)zb * sC;
#pragma unroll
  for (int i = 0; i < 4; ++i) {
#pragma unroll
    for (int r = 0; r < 4; ++r) {
      int gm = row0 + wr * 64 + i * 16 + q * 4 + r;
      if (gm < M) {
#pragma unroll
        for (int j = 0; j < 4; ++j) {
          int gn = col0 + wc * 64 + j * 16 + m15;
          float v = acc[i][j][r];
          if (DO_TANH) v = fast_tanh(v);
          if (OUT_MODE == 0) {
            atomicAdd(&Cf[(size_t)gm * ldc + gn], v);
          } else {
            short hi, lo; split2(v, hi, lo);
            Chs[(size_t)gm * ldc + gn] = hi;
            Cls[(size_t)gm * ldc + gn] = lo;
          }
        }
      }
    }
  }
}

// ---------------------------------------------------------------------------
// fp16 single-pass NT GEMM, BK=64, async staging, XOR-swizzled LDS.
// MODE 1: fp16 store (betas/alphas; batched via blockIdx.z)
// MODE 2: tanh + column-sum -> agg (V: 16384 rows = [Cat1;Cat2], agg[32][4096])
// ---------------------------------------------------------------------------
template <int MODE>
__global__ __launch_bounds__(256) void gemm_f16(
    const _Float16* __restrict__ A, int lda, long sA,
    const _Float16* __restrict__ B, int ldb, long sB,
    _Float16* __restrict__ C, int ldc, long sC,
    int K, float* __restrict__ agg)
{
  __shared__ __align__(16) _Float16 As[2 * 128 * 32];
  __shared__ __align__(16) _Float16 Bs[2 * 128 * 32];

  const int z = blockIdx.z;
  A += (size_t)z * sA;
  B += (size_t)z * sB;

  const int row0 = blockIdx.x * 128;
  const int col0 = blockIdx.y * 128;
  const int t = threadIdx.x, lane = t & 63, wave = t >> 6;
  const int wr = wave >> 1, wc = wave & 1;
  const int m15 = lane & 15, q = lane >> 4;

  const int srow = wave * 32 + (lane >> 2);
  const int cg   = ((lane & 3) ^ ((lane >> 3) & 3)) * 8;
  const _Float16* gA0 = A + (size_t)(row0 + srow) * lda + cg;
  const _Float16* gA1 = gA0 + (size_t)16 * lda;
  const _Float16* gB0 = B + (size_t)(col0 + srow) * ldb + cg;
  const _Float16* gB1 = gB0 + (size_t)16 * ldb;
  const _Float16* gA0b = gA0 + 32;
  const _Float16* gA1b = gA1 + 32;
  const _Float16* gB0b = gB0 + 32;
  const _Float16* gB1b = gB1 + 32;
  _Float16* lA0  = &As[(wave * 32) * 32];
  _Float16* lA1  = &As[(wave * 32 + 16) * 32];
  _Float16* lB0  = &Bs[(wave * 32) * 32];
  _Float16* lB1  = &Bs[(wave * 32 + 16) * 32];
  _Float16* lA0b = lA0 + 4096;
  _Float16* lA1b = lA1 + 4096;
  _Float16* lB0b = lB0 + 4096;
  _Float16* lB1b = lB1 + 4096;

  const int fs = (q ^ ((m15 >> 1) & 3)) * 8;
  int aoff[4], boff[4];
#pragma unroll
  for (int i = 0; i < 4; ++i) {
    aoff[i] = (wr * 64 + i * 16 + m15) * 32 + fs;
    boff[i] = (wc * 64 + i * 16 + m15) * 32 + fs;
  }

  float4_t acc[4][4];
#pragma unroll
  for (int i = 0; i < 4; ++i)
#pragma unroll
    for (int j = 0; j < 4; ++j) acc[i][j] = (float4_t)0.0f;

  for (int k0 = 0; k0 < K; k0 += 64) {
    gload16(gA0, lA0);  gload16(gA1, lA1);
    gload16(gB0, lB0);  gload16(gB1, lB1);
    gload16(gA0b, lA0b); gload16(gA1b, lA1b);
    gload16(gB0b, lB0b); gload16(gB1b, lB1b);
    gA0 += 64; gA1 += 64; gB0 += 64; gB1 += 64;
    gA0b += 64; gA1b += 64; gB0b += 64; gB1b += 64;
    __syncthreads();

#pragma unroll
    for (int h = 0; h < 2; ++h) {
      half8_t af[4], bfr[4];
#pragma unroll
      for (int i = 0; i < 4; ++i) af[i]  = *(const half8_t*)&As[h * 4096 + aoff[i]];
#pragma unroll
      for (int j = 0; j < 4; ++j) bfr[j] = *(const half8_t*)&Bs[h * 4096 + boff[j]];
#pragma unroll
      for (int i = 0; i < 4; ++i)
#pragma unroll
        for (int j = 0; j < 4; ++j)
          acc[i][j] = __builtin_amdgcn_mfma_f32_16x16x32_f16(af[i], bfr[j], acc[i][j], 0, 0, 0);
    }
    __syncthreads();
  }

  if (MODE == 2) {
    const int half_ = row0 >= 8192;
    const int b     = (row0 & 8191) >> 8;
#pragma unroll
    for (int j = 0; j < 4; ++j) {
      float s = 0.0f;
#pragma unroll
      for (int i = 0; i < 4; ++i)
#pragma unroll
        for (int r = 0; r < 4; ++r) s += fast_tanh(acc[i][j][r]);
      s += __shfl_xor(s, 16);
      s += __shfl_xor(s, 32);
      if (q == 0) {
        int col = col0 + wc * 64 + j * 16 + m15;
        atomicAdd(&agg[(size_t)b * 4096 + half_ * 2048 + col], s);
      }
    }
  } else {
    _Float16* Cp = C + (size_t)z * sC;
#pragma unroll
    for (int i = 0; i < 4; ++i)
#pragma unroll
      for (int r = 0; r < 4; ++r) {
        int gm = row0 + wr * 64 + i * 16 + q * 4 + r;
#pragma unroll
        for (int j = 0; j < 4; ++j) {
          int gn = col0 + wc * 64 + j * 16 + m15;
          Cp[(size_t)gm * ldc + gn] = (_Float16)acc[i][j][r];
        }
      }
  }
}

// --- input conv: fp32 [P;H] -> split bf16 planes + fp16 Cat left halves ---
__global__ __launch_bounds__(256) void conv_in(
    const float* __restrict__ P, const float* __restrict__ Hh,
    short* __restrict__ oh, short* __restrict__ ol, _Float16* __restrict__ cat)
{
  const int zz = blockIdx.z;
  const float* in = zz ? Hh : P;
  oh  += (size_t)zz * 8192 * 1024;
  ol  += (size_t)zz * 8192 * 1024;
  cat += (size_t)zz * 8192 * 2048;
  size_t i = ((size_t)blockIdx.x * 256 + threadIdx.x) * 4;
  float4 v = *(const float4*)&in[i];
  short4 h, l;
  split2(v.x, h.x, l.x); split2(v.y, h.y, l.y);
  split2(v.z, h.z, l.z); split2(v.w, h.w, l.w);
  *(short4*)&oh[i] = h;
  *(short4*)&ol[i] = l;
  size_t row = i >> 10;
  int col    = (int)(i & 1023);
  half4_t c16;
  c16.x = (_Float16)v.x; c16.y = (_Float16)v.y;
  c16.z = (_Float16)v.z; c16.w = (_Float16)v.w;
  *(half4_t*)&cat[row * 2048 + col] = c16;
}

// --- batched fp32 -> fp16 transpose of P (z<32) and H (z>=32): out[z][c][r] ---
__global__ __launch_bounds__(256) void transpose_f16_ph(
    const float* __restrict__ P, const float* __restrict__ Hh,
    _Float16* __restrict__ out)
{
  __shared__ float tile[32][33];
  const int zz = blockIdx.z;
  const float* in = (zz < 32 ? P : Hh) + (size_t)(zz & 31) * (256 * 1024);
  _Float16* o = out + (size_t)zz * (1024 * 256);
  const int tx = threadIdx.x & 31, ty = threadIdx.x >> 5;
  const int c0 = blockIdx.x * 32, r0 = blockIdx.y * 32;
#pragma unroll
  for (int i = 0; i < 4; ++i) {
    int r = ty + i * 8;
    tile[r][tx] = in[(size_t)(r0 + r) * 1024 + c0 + tx];
  }
  __syncthreads();
#pragma unroll
  for (int i = 0; i < 4; ++i) {
    int cc = ty + i * 8;
    o[(size_t)(c0 + cc) * 256 + r0 + tx] = (_Float16)tile[tx][cc];
  }
}

// --- fp32 -> split bf16 transpose: out[c][r] ---
__global__ __launch_bounds__(256) void transpose_split(
    const float* __restrict__ in, short* __restrict__ oh, short* __restrict__ ol,
    int R, int C)
{
  __shared__ float tile[32][33];
  const int tx = threadIdx.x & 31, ty = threadIdx.x >> 5;
  const int c0 = blockIdx.x * 32, r0 = blockIdx.y * 32;
#pragma unroll
  for (int i = 0; i < 4; ++i) {
    int r = ty + i * 8;
    tile[r][tx] = in[(size_t)(r0 + r) * C + c0 + tx];
  }
  __syncthreads();
#pragma unroll
  for (int i = 0; i < 4; ++i) {
    int cc = ty + i * 8;
    float v = tile[tx][cc];
    short hi, lo; split2(v, hi, lo);
    size_t o = (size_t)(c0 + cc) * R + r0 + tx;
    oh[o] = hi;
    ol[o] = lo;
  }
}

// --- fp32 -> fp16 transpose: out[c][r] ---
__global__ __launch_bounds__(256) void transpose_f16(
    const float* __restrict__ in, _Float16* __restrict__ out, int R, int C)
{
  __shared__ float tile[32][33];
  const int tx = threadIdx.x & 31, ty = threadIdx.x >> 5;
  const int c0 = blockIdx.x * 32, r0 = blockIdx.y * 32;
#pragma unroll
  for (int i = 0; i < 4; ++i) {
    int r = ty + i * 8;
    tile[r][tx] = in[(size_t)(r0 + r) * C + c0 + tx];
  }
  __syncthreads();
#pragma unroll
  for (int i = 0; i < 4; ++i) {
    int cc = ty + i * 8;
    out[(size_t)(c0 + cc) * R + r0 + tx] = (_Float16)tile[tx][cc];
  }
}

// --- fp16 [256x256] batched transpose (attn -> attnT), bit-copy as short ---
__global__ __launch_bounds__(256) void transpose_b2b(
    const short* __restrict__ in, short* __restrict__ out,
    int R, int C, long sIn, long sOut)
{
  __shared__ short tile[32][33];
  in  += (size_t)blockIdx.z * sIn;
  out += (size_t)blockIdx.z * sOut;
  const int tx = threadIdx.x & 31, ty = threadIdx.x >> 5;
  const int c0 = blockIdx.x * 32, r0 = blockIdx.y * 32;
#pragma unroll
  for (int i = 0; i < 4; ++i) {
    int r = ty + i * 8;
    tile[r][tx] = in[(size_t)(r0 + r) * C + c0 + tx];
  }
  __syncthreads();
#pragma unroll
  for (int i = 0; i < 4; ++i) {
    int cc = ty + i * 8;
    out[(size_t)(c0 + cc) * R + r0 + tx] = tile[tx][cc];
  }
}

__global__ __launch_bounds__(256) void zero_f32(float* __restrict__ p, int n)
{
  int i = blockIdx.x * 256 + threadIdx.x;
  if (i < n) p[i] = 0.0f;
}

// --- softmax over rows of 256 (one wave per row), fp32 -> fp16 ---
__global__ __launch_bounds__(256) void softmax_rows(
    const float* __restrict__ e, _Float16* __restrict__ attn)
{
  const int row  = blockIdx.x * 4 + (threadIdx.x >> 6);
  const int lane = threadIdx.x & 63;
  const float4 v = *(const float4*)&e[(size_t)row * 256 + lane * 4];
  float m = fmaxf(fmaxf(v.x, v.y), fmaxf(v.z, v.w));
#pragma unroll
  for (int off = 32; off; off >>= 1) m = fmaxf(m, __shfl_xor(m, off));
  float e0 = __expf(v.x - m), e1 = __expf(v.y - m);
  float e2 = __expf(v.z - m), e3 = __expf(v.w - m);
  float s = e0 + e1 + e2 + e3;
#pragma unroll
  for (int off = 32; off; off >>= 1) s += __shfl_xor(s, off);
  float inv = 1.0f / s;
  half4_t o;
  o.x = (_Float16)(e0 * inv); o.y = (_Float16)(e1 * inv);
  o.z = (_Float16)(e2 * inv); o.w = (_Float16)(e3 * inv);
  *(half4_t*)&attn[(size_t)row * 256 + lane * 4] = o;
}

// --- fp32 skinny GEMM k-slice, LDS-staged A (latency-tolerant) ---
// part[ks][32][N] = A[32][k-slice ks] @ W[k-slice ks][N].
// A slab staged in LDS once (coalesced); inner loop = streaming W loads only
// (independent, unroll-8 -> 8 in flight) + LDS-broadcast A + fma.
template <int KS>
__global__ __launch_bounds__(256) void skinny_part(
    const float* __restrict__ A, int lda,
    const float* __restrict__ W, int N,
    float* __restrict__ part)
{
  __shared__ float As[32][KS];
  const int n  = blockIdx.x * 256 + threadIdx.x;
  const int k0 = blockIdx.y * KS;
#pragma unroll
  for (int idx = threadIdx.x; idx < 32 * KS; idx += 256) {
    int m = idx / KS, k = idx - m * KS;
    As[m][k] = A[(size_t)m * lda + k0 + k];
  }
  __syncthreads();

  float acc[32];
#pragma unroll
  for (int m = 0; m < 32; ++m) acc[m] = 0.0f;
#pragma unroll 8
  for (int k = 0; k < KS; ++k) {
    float w = W[(size_t)(k0 + k) * N + n];
#pragma unroll
    for (int m = 0; m < 32; ++m)
      acc[m] = fmaf(As[m][k], w, acc[m]);
  }
  float* pp = part + (size_t)blockIdx.y * 32 * N;
#pragma unroll
  for (int m = 0; m < 32; ++m) pp[(size_t)m * N + n] = acc[m];
}

// --- a1[i] = tanh(b1[i&2047] + sum_{s<64} part[s][i]), i over 32*2048 ---
template <int S>
__global__ __launch_bounds__(256) void reduce_bias_tanh_f32(
    const float* __restrict__ part, const float* __restrict__ bias,
    float* __restrict__ outp)
{
  int i = blockIdx.x * 256 + threadIdx.x;
  float s = bias[i & 2047];
#pragma unroll
  for (int sl = 0; sl < S; ++sl) s += part[(size_t)sl * 65536 + i];
  outp[i] = fast_tanh(s);
}

// --- logits: block b: out[b] = tanh(sum_{s<S} c2p[s][b] + b2) @ W3 + b3 ---
template <int S>
__global__ __launch_bounds__(256) void logits_red(
    const float* __restrict__ part, const float* __restrict__ b2,
    const float* __restrict__ W3, const float* __restrict__ b3,
    float* __restrict__ out)
{
  const int b = blockIdx.x, t = threadIdx.x;
  float p0 = 0.f, p1 = 0.f, p2 = 0.f;
  for (int k = t; k < 2048; k += 256) {
    float a = b2[k];
#pragma unroll
    for (int sl = 0; sl < S; ++sl)
      a += part[((size_t)sl * 32 + b) * 2048 + k];
    a = fast_tanh(a);
    p0 += a * W3[k * 3 + 0];
    p1 += a * W3[k * 3 + 1];
    p2 += a * W3[k * 3 + 2];
  }
#pragma unroll
  for (int off = 32; off; off >>= 1) {
    p0 += __shfl_xor(p0, off);
    p1 += __shfl_xor(p1, off);
    p2 += __shfl_xor(p2, off);
  }
  __shared__ float red[4][3];
  if ((t & 63) == 0) {
    red[t >> 6][0] = p0; red[t >> 6][1] = p1; red[t >> 6][2] = p2;
  }
  __syncthreads();
  if (t < 3) out[b * 3 + t] = b3[t] + red[0][t] + red[1][t] + red[2][t] + red[3][t];
}

extern "C" void kernel_launch(void* const* d_in, const int* in_sizes, int n_in,
                              void* d_out, int out_size, void* d_ws, size_t ws_size,
                              hipStream_t stream) {
  (void)in_sizes; (void)n_in; (void)out_size; (void)ws_size;
  const float* P   = (const float*)d_in[0];
  const float* H   = (const float*)d_in[1];
  const float* W_F = (const float*)d_in[2];
  const float* W_G = (const float*)d_in[3];
  const float* W1  = (const float*)d_in[4];
  const float* b1  = (const float*)d_in[5];
  const float* W2  = (const float*)d_in[6];
  const float* b2  = (const float*)d_in[7];
  const float* W3  = (const float*)d_in[8];
  const float* b3  = (const float*)d_in[9];
  float* out = (float*)d_out;

  char* wsp = (char*)d_ws;
  auto alloc = [&](size_t bytes) {
    char* p = wsp;
    wsp += (bytes + 255) & ~(size_t)255;
    return p;
  };
  short*    Pp_h  = (short*)alloc(16384ull * 1024 * 2);     // [P;H] split planes
  short*    Pp_l  = (short*)alloc(16384ull * 1024 * 2);
  _Float16* Cat16 = (_Float16*)alloc(16384ull * 2048 * 2);  // [P|betas ; H|alphas]
  short*    Fbuf  = (short*)alloc(32ull * 1024 * 1024 * 2); // 64 MB multi-use
  short*    WFT_h = (short*)alloc(1024ull * 1024 * 2);
  short*    WFT_l = (short*)alloc(1024ull * 1024 * 2);
  _Float16* WGT16 = (_Float16*)alloc(2048ull * 2048 * 2);
  float*    eijs  = (float*)alloc(32ull * 256 * 256 * 4);
  _Float16* attn  = (_Float16*)alloc(32ull * 256 * 256 * 2);
  _Float16* attnT = (_Float16*)alloc(32ull * 256 * 256 * 2);
  float*    agg   = (float*)alloc(32ull * 4096 * 4);

  // Fbuf phase 1: F split planes (2 x 32 MB)
  short* F_h = Fbuf;
  short* F_l = Fbuf + 16384ull * 1024;
  // Fbuf phase 2: PHbT fp16 (64 batches x [1024][256] = 32 MB)
  _Float16* PHbT = (_Float16*)Fbuf;
  _Float16* PbT  = PHbT;
  _Float16* HbT  = PHbT + 32ull * 1024 * 256;
  // classifier scratch aliases Pp planes (dead after the F GEMM):
  float* c1p = (float*)Pp_h;                 // 64 slices x [32][2048] = 16 MB
  float* c2p = c1p + 64ull * 32 * 2048;      // 32 slices x [32][2048] = 8 MB
  float* a1f = c2p + 32ull * 32 * 2048;      // [32][2048] fp32

  // 1. input conversions, weight transposes  (R4 order, verbatim)
  conv_in<<<dim3(8192, 1, 2), 256, 0, stream>>>(P, H, Pp_h, Pp_l, Cat16);
  transpose_split<<<dim3(32, 32, 1), 256, 0, stream>>>(W_F, WFT_h, WFT_l, 1024, 1024);
  transpose_f16<<<dim3(64, 64, 1), 256, 0, stream>>>(W_G, WGT16, 2048, 2048);

  // 2. F = tanh([P;H] @ W_F), split bf16x3 (sync staging)
  gemm_nt_split<1, 1><<<dim3(128, 8, 1), 256, 0, stream>>>(
      Pp_h, Pp_l, 1024, 0, WFT_h, WFT_l, 1024, 0,
      F_h, F_l, 1024, 0, 16384, 1024, 1);

  // 3. scores E[z] = F_p[z] @ F_h[z]^T, split bf16x3, split-K x4 (atomic fp32)
  zero_f32<<<8192, 256, 0, stream>>>(eijs, 32 * 256 * 256);
  gemm_nt_split<0, 0><<<dim3(2, 2, 128), 256, 0, stream>>>(
      F_h, F_l, 1024, 256 * 1024,
      F_h + 8192ull * 1024, F_l + 8192ull * 1024, 1024, 256 * 1024,
      eijs, nullptr, 256, 65536, 256, 1024, 4);

  // 4. softmax -> fp16 attn; attn^T; P^T/H^T fp16 into Fbuf
  softmax_rows<<<2048, 256, 0, stream>>>(eijs, attn);
  transpose_b2b<<<dim3(8, 8, 32), 256, 0, stream>>>(
      (const short*)attn, (short*)attnT, 256, 256, 65536, 65536);
  transpose_f16_ph<<<dim3(32, 8, 64), 256, 0, stream>>>(P, H, PHbT);

  // 5. betas = attn @ H -> Cat1 right; alphas = attn^T @ P -> Cat2 right (fp16)
  gemm_f16<1><<<dim3(2, 8, 32), 256, 0, stream>>>(
      attn, 256, 65536, HbT, 256, 1024 * 256,
      Cat16 + 1024, 2048, 256 * 2048, 256, nullptr);
  gemm_f16<1><<<dim3(2, 8, 32), 256, 0, stream>>>(
      attnT, 256, 65536, PbT, 256, 1024 * 256,
      Cat16 + 8192ull * 2048 + 1024, 2048, 256 * 2048, 256, nullptr);

  // 6. V = tanh(Cat @ W_G) fused column-sum -> agg (fp16, BK=64)
  zero_f32<<<512, 256, 0, stream>>>(agg, 32 * 4096);
  gemm_f16<2><<<dim3(128, 16, 1), 256, 0, stream>>>(
      Cat16, 2048, 0, WGT16, 2048, 0, nullptr, 0, 0, 2048, agg);

  // 7. classifier: LDS-staged fp32 skinny GEMMs + unrolled reductions
  skinny_part<64><<<dim3(8, 64), 256, 0, stream>>>(agg, 4096, W1, 2048, c1p);
  reduce_bias_tanh_f32<64><<<256, 256, 0, stream>>>(c1p, b1, a1f);
  skinny_part<64><<<dim3(8, 32), 256, 0, stream>>>(a1f, 2048, W2, 2048, c2p);
  logits_red<32><<<32, 256, 0, stream>>>(c2p, b2, W3, b3, out);
}

// Round 9
// 652.576 us; speedup vs baseline: 1.2499x; 1.0197x over previous
//
#include <hip/hip_runtime.h>
#include <hip/hip_bf16.h>
#include <stdint.h>

// Shapes: B=32, L=256, D=1024, ALIGN=1024, FF=2048, NC=3
// Precision plan:
//  - F proj, E scores: bf16x3 split (~fp32) -- the softmax-sensitive path
//  - attn, betas/alphas, V=tanh(Cat@W_G): fp16 single (store rounding dominates)
//  - classifier: fp32 skinny GEMMs, latency-tolerant (R8-validated)
// R9: (a) dispatch consolidation 17->13 (fused_in back [bisect-proven neutral],
//     merged weight transposes, E k-slice partial stores kill zero+atomics,
//     agg zero folded into softmax); (b) V/betas/alphas on 32x32x16 fp16 MFMA
//     (2382 vs 2075 TF ubench; C/D mapping per verified m74/m101).

typedef __attribute__((ext_vector_type(8)))  short    short8_t;   // 8 bf16
typedef __attribute__((ext_vector_type(4)))  float    float4_t;
typedef __attribute__((ext_vector_type(16))) float    float16_t;
typedef __attribute__((ext_vector_type(8)))  _Float16 half8_t;
typedef __attribute__((ext_vector_type(4)))  _Float16 half4_t;

#define DEVI static __device__ __forceinline__

DEVI short f2bf(float f) {
  union { float f; unsigned u; } v; v.f = f;
  unsigned r = v.u + 0x7fffu + ((v.u >> 16) & 1u);   // RNE
  return (short)(r >> 16);
}
DEVI float bf2f(short s) {
  union { unsigned u; float f; } v;
  v.u = ((unsigned)(unsigned short)s) << 16;
  return v.f;
}
DEVI void split2(float x, short& hi, short& lo) {
  hi = f2bf(x);
  lo = f2bf(x - bf2f(hi));
}
DEVI float fast_tanh(float x) {
  float e = __expf(2.0f * x);
  return 1.0f - 2.0f / (e + 1.0f);
}
DEVI void gload16(const void* g, void* l) {
  __builtin_amdgcn_global_load_lds(
      (const __attribute__((address_space(1))) void*)g,
      (__attribute__((address_space(3))) void*)l, 16, 0, 0);
}

// ---------------------------------------------------------------------------
// Split-bf16 NT GEMM (A=Ah+Al, B=Bh+Bl), 128x128 tile, BK=32, 16x16x32 MFMA,
// SYNC staging (VGPR roundtrip, [40] pad). blockIdx.z = batch*kslices + kslice.
// OUT_MODE: 0 = fp32 PLAIN store to per-(batch,kslice) plane z (no atomics),
//           1 = split bf16 store (optional tanh).
// ---------------------------------------------------------------------------
template <int DO_TANH, int OUT_MODE>
__global__ __launch_bounds__(256) void gemm_nt_split(
    const short* __restrict__ Ah, const short* __restrict__ Al, int lda, long sA,
    const short* __restrict__ Bh, const short* __restrict__ Bl, int ldb, long sB,
    void* __restrict__ Ch, void* __restrict__ Cl, int ldc, long sC,
    int M, int K, int kslices)
{
  __shared__ __align__(16) short Ash[128][40];
  __shared__ __align__(16) short Asl[128][40];
  __shared__ __align__(16) short Bsh[128][40];
  __shared__ __align__(16) short Bsl[128][40];

  const int z  = blockIdx.z;
  const int zb = z / kslices;
  const int zk = z - zb * kslices;
  const int Ksub = K / kslices;
  const int kbeg = zk * Ksub, kend = kbeg + Ksub;

  Ah += (size_t)zb * sA;  Al += (size_t)zb * sA;
  Bh += (size_t)zb * sB;  Bl += (size_t)zb * sB;

  const int row0 = blockIdx.x * 128;
  const int col0 = blockIdx.y * 128;

  const int t    = threadIdx.x;
  const int lane = t & 63;
  const int wave = t >> 6;
  const int wr = wave >> 1, wc = wave & 1;
  const int m15 = lane & 15, q = lane >> 4;

  float4_t acc[4][4];
#pragma unroll
  for (int i = 0; i < 4; ++i)
#pragma unroll
    for (int j = 0; j < 4; ++j) acc[i][j] = (float4_t)0.0f;

  for (int k0 = kbeg; k0 < kend; k0 += 32) {
#pragma unroll
    for (int i = 0; i < 2; ++i) {
      int c  = t + 256 * i;       // 0..511
      int r  = c >> 2;            // 0..127
      int kc = (c & 3) << 3;      // 0,8,16,24
      size_t ao = (size_t)(row0 + r) * lda + k0 + kc;
      size_t bo = (size_t)(col0 + r) * ldb + k0 + kc;
      *(int4*)(&Ash[r][kc]) = *(const int4*)(Ah + ao);
      *(int4*)(&Asl[r][kc]) = *(const int4*)(Al + ao);
      *(int4*)(&Bsh[r][kc]) = *(const int4*)(Bh + bo);
      *(int4*)(&Bsl[r][kc]) = *(const int4*)(Bl + bo);
    }
    __syncthreads();

    short8_t ah[4], al[4];
#pragma unroll
    for (int i = 0; i < 4; ++i) {
      ah[i] = *(const short8_t*)(&Ash[wr * 64 + i * 16 + m15][q * 8]);
      al[i] = *(const short8_t*)(&Asl[wr * 64 + i * 16 + m15][q * 8]);
    }
#pragma unroll
    for (int j = 0; j < 4; ++j) {
      short8_t bh = *(const short8_t*)(&Bsh[wc * 64 + j * 16 + m15][q * 8]);
      short8_t bl = *(const short8_t*)(&Bsl[wc * 64 + j * 16 + m15][q * 8]);
#pragma unroll
      for (int i = 0; i < 4; ++i) {
        acc[i][j] = __builtin_amdgcn_mfma_f32_16x16x32_bf16(ah[i], bh, acc[i][j], 0, 0, 0);
        acc[i][j] = __builtin_amdgcn_mfma_f32_16x16x32_bf16(ah[i], bl, acc[i][j], 0, 0, 0);
        acc[i][j] = __builtin_amdgcn_mfma_f32_16x16x32_bf16(al[i], bh, acc[i][j], 0, 0, 0);
      }
    }
    __syncthreads();
  }

  short* Chs = (short*)Ch + (size_t)zb * sC;
  short* Cls = (short*)Cl + (size_t)zb * sC;
  float* Cf  = (float*)Ch + (size_t)z  * sC;   // per-(batch,kslice) plane
#pragma unroll
  for (int i = 0; i < 4; ++i) {
#pragma unroll
    for (int r = 0; r < 4; ++r) {
      int gm = row0 + wr * 64 + i * 16 + q * 4 + r;
      if (gm < M) {
#pragma unroll
        for (int j = 0; j < 4; ++j) {
          int gn = col0 + wc * 64 + j * 16 + m15;
          float v = acc[i][j][r];
          if (DO_TANH) v = fast_tanh(v);
          if (OUT_MODE == 0) {
            Cf[(size_t)gm * ldc + gn] = v;
          } else {
            short hi, lo; split2(v, hi, lo);
            Chs[(size_t)gm * ldc + gn] = hi;
            Cls[(size_t)gm * ldc + gn] = lo;
          }
        }
      }
    }
  }
}

// ---------------------------------------------------------------------------
// fp16 single-pass NT GEMM on 32x32x16 MFMA, 128x128 tile, BK=64, async
// global_load_lds staging, XOR chunk-swizzled LDS. Wave = 2x2 of 32x32.
// C/D mapping (verified m74/m101): col=lane&31, row=(reg&3)+8*(reg>>2)+4*(lane>>5)
// MODE 1: fp16 store (betas/alphas; batched via blockIdx.z)
// MODE 2: tanh + column-sum -> agg (V: 16384 rows = [Cat1;Cat2], agg[32][4096])
// ---------------------------------------------------------------------------
template <int MODE>
__global__ __launch_bounds__(256) void gemm_f16_32(
    const _Float16* __restrict__ A, int lda, long sA,
    const _Float16* __restrict__ B, int ldb, long sB,
    _Float16* __restrict__ C, int ldc, long sC,
    int K, float* __restrict__ agg)
{
  __shared__ __align__(16) _Float16 As[2 * 128 * 32];
  __shared__ __align__(16) _Float16 Bs[2 * 128 * 32];

  const int z = blockIdx.z;
  A += (size_t)z * sA;
  B += (size_t)z * sB;

  const int row0 = blockIdx.x * 128;
  const int col0 = blockIdx.y * 128;
  const int t = threadIdx.x, lane = t & 63, wave = t >> 6;
  const int wr = wave >> 1, wc = wave & 1;
  const int l31 = lane & 31, h5 = lane >> 5;

  // staging: wave w stages rows [w*32,w*32+32), 16 rows per gload16 call.
  // lane l -> row base+(l>>2), LDS slot l&3; global chunk (l&3)^((l>>3)&3).
  const int srow = wave * 32 + (lane >> 2);
  const int cg   = ((lane & 3) ^ ((lane >> 3) & 3)) * 8;
  const _Float16* gA0 = A + (size_t)(row0 + srow) * lda + cg;
  const _Float16* gA1 = gA0 + (size_t)16 * lda;
  const _Float16* gB0 = B + (size_t)(col0 + srow) * ldb + cg;
  const _Float16* gB1 = gB0 + (size_t)16 * ldb;
  const _Float16* gA0b = gA0 + 32;
  const _Float16* gA1b = gA1 + 32;
  const _Float16* gB0b = gB0 + 32;
  const _Float16* gB1b = gB1 + 32;
  _Float16* lA0  = &As[(wave * 32) * 32];
  _Float16* lA1  = &As[(wave * 32 + 16) * 32];
  _Float16* lB0  = &Bs[(wave * 32) * 32];
  _Float16* lB1  = &Bs[(wave * 32 + 16) * 32];
  _Float16* lA0b = lA0 + 4096;
  _Float16* lA1b = lA1 + 4096;
  _Float16* lB0b = lB0 + 4096;
  _Float16* lB1b = lB1 + 4096;

  // fragment offsets: A[m=l31][k=h5*8+j] (k-step s adds 16); row base is a
  // multiple of 32 so swizzle term = (l31>>1)&3. chunk = s*2 + h5.
  const int sw = (l31 >> 1) & 3;
  int coff[2];
#pragma unroll
  for (int s = 0; s < 2; ++s) coff[s] = (((s * 2 + h5) ^ sw)) * 8;
  int arow[2], brow[2];
#pragma unroll
  for (int i = 0; i < 2; ++i) {
    arow[i] = (wr * 64 + i * 32 + l31) * 32;
    brow[i] = (wc * 64 + i * 32 + l31) * 32;
  }

  float16_t acc[2][2];
#pragma unroll
  for (int i = 0; i < 2; ++i)
#pragma unroll
    for (int j = 0; j < 2; ++j) acc[i][j] = (float16_t)0.0f;

  for (int k0 = 0; k0 < K; k0 += 64) {
    gload16(gA0, lA0);  gload16(gA1, lA1);
    gload16(gB0, lB0);  gload16(gB1, lB1);
    gload16(gA0b, lA0b); gload16(gA1b, lA1b);
    gload16(gB0b, lB0b); gload16(gB1b, lB1b);
    gA0 += 64; gA1 += 64; gB0 += 64; gB1 += 64;
    gA0b += 64; gA1b += 64; gB0b += 64; gB1b += 64;
    __syncthreads();

#pragma unroll
    for (int h = 0; h < 2; ++h) {
#pragma unroll
      for (int s = 0; s < 2; ++s) {
        half8_t a0 = *(const half8_t*)&As[h * 4096 + arow[0] + coff[s]];
        half8_t a1 = *(const half8_t*)&As[h * 4096 + arow[1] + coff[s]];
        half8_t b0 = *(const half8_t*)&Bs[h * 4096 + brow[0] + coff[s]];
        half8_t b1 = *(const half8_t*)&Bs[h * 4096 + brow[1] + coff[s]];
        acc[0][0] = __builtin_amdgcn_mfma_f32_32x32x16_f16(a0, b0, acc[0][0], 0, 0, 0);
        acc[0][1] = __builtin_amdgcn_mfma_f32_32x32x16_f16(a0, b1, acc[0][1], 0, 0, 0);
        acc[1][0] = __builtin_amdgcn_mfma_f32_32x32x16_f16(a1, b0, acc[1][0], 0, 0, 0);
        acc[1][1] = __builtin_amdgcn_mfma_f32_32x32x16_f16(a1, b1, acc[1][1], 0, 0, 0);
      }
    }
    __syncthreads();
  }

  if (MODE == 2) {
    const int half_ = row0 >= 8192;
    const int bb    = (row0 & 8191) >> 8;
#pragma unroll
    for (int j = 0; j < 2; ++j) {
      float s = 0.0f;
#pragma unroll
      for (int i = 0; i < 2; ++i)
#pragma unroll
        for (int r = 0; r < 16; ++r) s += fast_tanh(acc[i][j][r]);
      s += __shfl_xor(s, 32);
      if (h5 == 0) {
        int col = col0 + wc * 64 + j * 32 + l31;
        atomicAdd(&agg[(size_t)bb * 4096 + half_ * 2048 + col], s);
      }
    }
  } else {
    _Float16* Cp = C + (size_t)z * sC;
#pragma unroll
    for (int i = 0; i < 2; ++i)
#pragma unroll
      for (int j = 0; j < 2; ++j)
#pragma unroll
        for (int r = 0; r < 16; ++r) {
          int gm = row0 + wr * 64 + i * 32 + (r & 3) + 8 * (r >> 2) + 4 * h5;
          int gn = col0 + wc * 64 + j * 32 + l31;
          Cp[(size_t)gm * ldc + gn] = (_Float16)acc[i][j][r];
        }
  }
}

// --- fused input: P/H -> split bf16 planes + fp16 Cat left half + fp16 PH^T ---
// grid (32 c-tiles, 8 r-tiles, 64): z<32 = P batch z, z>=32 = H batch z-32
__global__ __launch_bounds__(256) void fused_in(
    const float* __restrict__ P, const float* __restrict__ Hh,
    short* __restrict__ oh, short* __restrict__ ol,
    _Float16* __restrict__ cat, _Float16* __restrict__ phT)
{
  __shared__ float tile[32][33];
  const int z = blockIdx.z;
  const float* in = (z < 32 ? P : Hh) + (size_t)(z & 31) * (256 * 1024);
  const int tx = threadIdx.x & 31, ty = threadIdx.x >> 5;
  const int c0 = blockIdx.x * 32, r0 = blockIdx.y * 32;
#pragma unroll
  for (int i = 0; i < 4; ++i) {
    int r = ty + i * 8;
    float v = in[(size_t)(r0 + r) * 1024 + c0 + tx];
    tile[r][tx] = v;
    size_t grow = (size_t)z * 256 + r0 + r;   // 0..16383 ([P;H] row)
    short hi, lo; split2(v, hi, lo);
    oh[grow * 1024 + c0 + tx] = hi;
    ol[grow * 1024 + c0 + tx] = lo;
    cat[grow * 2048 + c0 + tx] = (_Float16)v;
  }
  __syncthreads();
  _Float16* o = phT + (size_t)z * (1024 * 256);
#pragma unroll
  for (int i = 0; i < 4; ++i) {
    int cc = ty + i * 8;
    o[(size_t)(c0 + cc) * 256 + r0 + tx] = (_Float16)tile[tx][cc];
  }
}

// --- combined weight transposes: z=0 -> W_G fp16^T (2048^2, 64x64 tiles);
//     z=1 -> W_F split^T (1024^2, x<32 && y<32 active) ---
__global__ __launch_bounds__(256) void weights_tr(
    const float* __restrict__ W_F, const float* __restrict__ W_G,
    short* __restrict__ wfh, short* __restrict__ wfl, _Float16* __restrict__ wgt)
{
  __shared__ float tile[32][33];
  const int tx = threadIdx.x & 31, ty = threadIdx.x >> 5;
  if (blockIdx.z == 0) {
    const int c0 = blockIdx.x * 32, r0 = blockIdx.y * 32;
#pragma unroll
    for (int i = 0; i < 4; ++i) {
      int r = ty + i * 8;
      tile[r][tx] = W_G[(size_t)(r0 + r) * 2048 + c0 + tx];
    }
    __syncthreads();
#pragma unroll
    for (int i = 0; i < 4; ++i) {
      int cc = ty + i * 8;
      wgt[(size_t)(c0 + cc) * 2048 + r0 + tx] = (_Float16)tile[tx][cc];
    }
  } else {
    if (blockIdx.x >= 32 || blockIdx.y >= 32) return;
    const int c0 = blockIdx.x * 32, r0 = blockIdx.y * 32;
#pragma unroll
    for (int i = 0; i < 4; ++i) {
      int r = ty + i * 8;
      tile[r][tx] = W_F[(size_t)(r0 + r) * 1024 + c0 + tx];
    }
    __syncthreads();
#pragma unroll
    for (int i = 0; i < 4; ++i) {
      int cc = ty + i * 8;
      float v = tile[tx][cc];
      short hi, lo; split2(v, hi, lo);
      size_t o = (size_t)(c0 + cc) * 1024 + r0 + tx;
      wfh[o] = hi;
      wfl[o] = lo;
    }
  }
}

// --- fp16 [256x256] batched transpose (attn -> attnT), bit-copy as short ---
__global__ __launch_bounds__(256) void transpose_b2b(
    const short* __restrict__ in, short* __restrict__ out,
    int R, int C, long sIn, long sOut)
{
  __shared__ short tile[32][33];
  in  += (size_t)blockIdx.z * sIn;
  out += (size_t)blockIdx.z * sOut;
  const int tx = threadIdx.x & 31, ty = threadIdx.x >> 5;
  const int c0 = blockIdx.x * 32, r0 = blockIdx.y * 32;
#pragma unroll
  for (int i = 0; i < 4; ++i) {
    int r = ty + i * 8;
    tile[r][tx] = in[(size_t)(r0 + r) * C + c0 + tx];
  }
  __syncthreads();
#pragma unroll
  for (int i = 0; i < 4; ++i) {
    int cc = ty + i * 8;
    out[(size_t)(c0 + cc) * R + r0 + tx] = tile[tx][cc];
  }
}

// --- softmax over rows of 256: sums 4 k-slice partials, also zeroes agg ---
__global__ __launch_bounds__(256) void softmax_rows4(
    const float* __restrict__ ep, _Float16* __restrict__ attn,
    float* __restrict__ agg)
{
  if (blockIdx.x < 512) agg[(size_t)blockIdx.x * 256 + threadIdx.x] = 0.0f;
  const int row  = blockIdx.x * 4 + (threadIdx.x >> 6);
  const int lane = threadIdx.x & 63;
  const int zb = row >> 8, r = row & 255;
  const float* b0 = ep + (size_t)(zb * 4) * 65536 + r * 256 + lane * 4;
  float4 v0 = *(const float4*)b0;
  float4 v1 = *(const float4*)(b0 + 65536);
  float4 v2 = *(const float4*)(b0 + 2 * 65536);
  float4 v3 = *(const float4*)(b0 + 3 * 65536);
  float x0 = v0.x + v1.x + v2.x + v3.x;
  float x1 = v0.y + v1.y + v2.y + v3.y;
  float x2 = v0.z + v1.z + v2.z + v3.z;
  float x3 = v0.w + v1.w + v2.w + v3.w;
  float m = fmaxf(fmaxf(x0, x1), fmaxf(x2, x3));
#pragma unroll
  for (int off = 32; off; off >>= 1) m = fmaxf(m, __shfl_xor(m, off));
  float e0 = __expf(x0 - m), e1 = __expf(x1 - m);
  float e2 = __expf(x2 - m), e3 = __expf(x3 - m);
  float s = e0 + e1 + e2 + e3;
#pragma unroll
  for (int off = 32; off; off >>= 1) s += __shfl_xor(s, off);
  float inv = 1.0f / s;
  half4_t o;
  o.x = (_Float16)(e0 * inv); o.y = (_Float16)(e1 * inv);
  o.z = (_Float16)(e2 * inv); o.w = (_Float16)(e3 * inv);
  *(half4_t*)&attn[(size_t)row * 256 + lane * 4] = o;
}

// --- fp32 skinny GEMM k-slice, LDS-staged A (latency-tolerant, R8) ---
template <int KS>
__global__ __launch_bounds__(256) void skinny_part(
    const float* __restrict__ A, int lda,
    const float* __restrict__ W, int N,
    float* __restrict__ part)
{
  __shared__ float As[32][KS];
  const int n  = blockIdx.x * 256 + threadIdx.x;
  const int k0 = blockIdx.y * KS;
#pragma unroll
  for (int idx = threadIdx.x; idx < 32 * KS; idx += 256) {
    int m = idx / KS, k = idx - m * KS;
    As[m][k] = A[(size_t)m * lda + k0 + k];
  }
  __syncthreads();

  float acc[32];
#pragma unroll
  for (int m = 0; m < 32; ++m) acc[m] = 0.0f;
#pragma unroll 8
  for (int k = 0; k < KS; ++k) {
    float w = W[(size_t)(k0 + k) * N + n];
#pragma unroll
    for (int m = 0; m < 32; ++m)
      acc[m] = fmaf(As[m][k], w, acc[m]);
  }
  float* pp = part + (size_t)blockIdx.y * 32 * N;
#pragma unroll
  for (int m = 0; m < 32; ++m) pp[(size_t)m * N + n] = acc[m];
}

// --- a1[i] = tanh(b1[i&2047] + sum_{s<S} part[s][i]) ---
template <int S>
__global__ __launch_bounds__(256) void reduce_bias_tanh_f32(
    const float* __restrict__ part, const float* __restrict__ bias,
    float* __restrict__ outp)
{
  int i = blockIdx.x * 256 + threadIdx.x;
  float s = bias[i & 2047];
#pragma unroll
  for (int sl = 0; sl < S; ++sl) s += part[(size_t)sl * 65536 + i];
  outp[i] = fast_tanh(s);
}

// --- logits: block b: out[b] = tanh(sum_{s<S} c2p[s][b] + b2) @ W3 + b3 ---
template <int S>
__global__ __launch_bounds__(256) void logits_red(
    const float* __restrict__ part, const float* __restrict__ b2,
    const float* __restrict__ W3, const float* __restrict__ b3,
    float* __restrict__ out)
{
  const int b = blockIdx.x, t = threadIdx.x;
  float p0 = 0.f, p1 = 0.f, p2 = 0.f;
  for (int k = t; k < 2048; k += 256) {
    float a = b2[k];
#pragma unroll
    for (int sl = 0; sl < S; ++sl)
      a += part[((size_t)sl * 32 + b) * 2048 + k];
    a = fast_tanh(a);
    p0 += a * W3[k * 3 + 0];
    p1 += a * W3[k * 3 + 1];
    p2 += a * W3[k * 3 + 2];
  }
#pragma unroll
  for (int off = 32; off; off >>= 1) {
    p0 += __shfl_xor(p0, off);
    p1 += __shfl_xor(p1, off);
    p2 += __shfl_xor(p2, off);
  }
  __shared__ float red[4][3];
  if ((t & 63) == 0) {
    red[t >> 6][0] = p0; red[t >> 6][1] = p1; red[t >> 6][2] = p2;
  }
  __syncthreads();
  if (t < 3) out[b * 3 + t] = b3[t] + red[0][t] + red[1][t] + red[2][t] + red[3][t];
}

extern "C" void kernel_launch(void* const* d_in, const int* in_sizes, int n_in,
                              void* d_out, int out_size, void* d_ws, size_t ws_size,
                              hipStream_t stream) {
  (void)in_sizes; (void)n_in; (void)out_size; (void)ws_size;
  const float* P   = (const float*)d_in[0];
  const float* H   = (const float*)d_in[1];
  const float* W_F = (const float*)d_in[2];
  const float* W_G = (const float*)d_in[3];
  const float* W1  = (const float*)d_in[4];
  const float* b1  = (const float*)d_in[5];
  const float* W2  = (const float*)d_in[6];
  const float* b2  = (const float*)d_in[7];
  const float* W3  = (const float*)d_in[8];
  const float* b3  = (const float*)d_in[9];
  float* out = (float*)d_out;

  char* wsp = (char*)d_ws;
  auto alloc = [&](size_t bytes) {
    char* p = wsp;
    wsp += (bytes + 255) & ~(size_t)255;
    return p;
  };
  short*    Pp_h  = (short*)alloc(16384ull * 1024 * 2);     // [P;H] split planes
  short*    Pp_l  = (short*)alloc(16384ull * 1024 * 2);
  _Float16* Cat16 = (_Float16*)alloc(16384ull * 2048 * 2);  // [P|betas ; H|alphas]
  _Float16* PHbT  = (_Float16*)alloc(64ull * 1024 * 256 * 2); // P^T,H^T fp16
  short*    F_h   = (short*)alloc(16384ull * 1024 * 2);
  short*    F_l   = (short*)alloc(16384ull * 1024 * 2);
  short*    WFT_h = (short*)alloc(1024ull * 1024 * 2);
  short*    WFT_l = (short*)alloc(1024ull * 1024 * 2);
  _Float16* WGT16 = (_Float16*)alloc(2048ull * 2048 * 2);
  _Float16* attn  = (_Float16*)alloc(32ull * 256 * 256 * 2);
  _Float16* attnT = (_Float16*)alloc(32ull * 256 * 256 * 2);
  float*    agg   = (float*)alloc(32ull * 4096 * 4);

  _Float16* PbT = PHbT;
  _Float16* HbT = PHbT + 32ull * 1024 * 256;
  // aliases into dead regions:
  float* epart = (float*)Pp_h;               // 128 planes x [256][256] = 32 MB
  float* c1p   = (float*)Pp_l;               // 64 x [32][2048] = 16 MB
  float* c2p   = c1p + 64ull * 32 * 2048;    // 32 x [32][2048] = 8 MB
  float* a1f   = c2p + 32ull * 32 * 2048;    // [32][2048]

  // 1. fused input stage + merged weight transposes
  fused_in<<<dim3(32, 8, 64), 256, 0, stream>>>(P, H, Pp_h, Pp_l, Cat16, PHbT);
  weights_tr<<<dim3(64, 64, 2), 256, 0, stream>>>(W_F, W_G, WFT_h, WFT_l, WGT16);

  // 2. F = tanh([P;H] @ W_F), split bf16x3 (sync staging)
  gemm_nt_split<1, 1><<<dim3(128, 8, 1), 256, 0, stream>>>(
      Pp_h, Pp_l, 1024, 0, WFT_h, WFT_l, 1024, 0,
      F_h, F_l, 1024, 0, 16384, 1024, 1);
  // (Pp planes dead from here; epart/c1p alias them)

  // 3. scores E: split bf16x3, split-K x4, plain partial stores (no atomics)
  gemm_nt_split<0, 0><<<dim3(2, 2, 128), 256, 0, stream>>>(
      F_h, F_l, 1024, 256 * 1024,
      F_h + 8192ull * 1024, F_l + 8192ull * 1024, 1024, 256 * 1024,
      epart, nullptr, 256, 65536, 256, 1024, 4);

  // 4. softmax over summed partials -> fp16 attn (+ zeroes agg); attn^T
  softmax_rows4<<<2048, 256, 0, stream>>>(epart, attn, agg);
  transpose_b2b<<<dim3(8, 8, 32), 256, 0, stream>>>(
      (const short*)attn, (short*)attnT, 256, 256, 65536, 65536);

  // 5. betas = attn @ H -> Cat1 right; alphas = attn^T @ P -> Cat2 right (fp16, 32x32)
  gemm_f16_32<1><<<dim3(2, 8, 32), 256, 0, stream>>>(
      attn, 256, 65536, HbT, 256, 1024 * 256,
      Cat16 + 1024, 2048, 256 * 2048, 256, nullptr);
  gemm_f16_32<1><<<dim3(2, 8, 32), 256, 0, stream>>>(
      attnT, 256, 65536, PbT, 256, 1024 * 256,
      Cat16 + 8192ull * 2048 + 1024, 2048, 256 * 2048, 256, nullptr);

  // 6. V = tanh(Cat @ W_G) fused column-sum -> agg (fp16, 32x32, BK=64)
  gemm_f16_32<2><<<dim3(128, 16, 1), 256, 0, stream>>>(
      Cat16, 2048, 0, WGT16, 2048, 0, nullptr, 0, 0, 2048, agg);

  // 7. classifier: LDS-staged fp32 skinny GEMMs + unrolled reductions (R8)
  skinny_part<64><<<dim3(8, 64), 256, 0, stream>>>(agg, 4096, W1, 2048, c1p);
  reduce_bias_tanh_f32<64><<<256, 256, 0, stream>>>(c1p, b1, a1f);
  skinny_part<64><<<dim3(8, 32), 256, 0, stream>>>(a1f, 2048, W2, 2048, c2p);
  logits_red<32><<<32, 256, 0, stream>>>(c2p, b2, W3, b3, out);
}